// Round 8
// baseline (500.777 us; speedup 1.0000x reference)
//
#include <hip/hip_runtime.h>
#include <hip/hip_bf16.h>
#include <hip/hip_fp16.h>

#define NN   100000
#define EE   1600000
#define ETOT (EE + NN)
#define GG   256
#define BNEPS 1e-5f
#define NBK  391          // buckets of 256 nodes: (NN+255)/256
#define PADTOT (ETOT + NBK * 4096 + 64)
#define PSPLIT 16

typedef float floatx2 __attribute__((ext_vector_type(2)));
typedef short s16x8 __attribute__((ext_vector_type(8)));
typedef float f32x4v __attribute__((ext_vector_type(4)));

__device__ __forceinline__ unsigned short f2bf(float f) {
    unsigned u = __float_as_uint(f);
    unsigned r = u + 0x7FFF + ((u >> 16) & 1);
    return (unsigned short)(r >> 16);
}
__device__ __forceinline__ float bf2f(unsigned short b) {
    return __uint_as_float(((unsigned)b) << 16);
}
// packed 2xfp32 FMA → v_pk_fma_f32
__device__ __forceinline__ floatx2 pkfma(floatx2 a, floatx2 b, floatx2 c) {
    return __builtin_elementwise_fma(a, b, c);
}

// ---------------- CSR build: bucketed partition (single-writer cache lines) --

__global__ __launch_bounds__(256) void bucket_count_kernel(
    const int* __restrict__ ei, int* __restrict__ bucket_cnt)
{
    __shared__ int cnt[NBK];
    for (int i = threadIdx.x; i < NBK; i += 256) cnt[i] = 0;
    __syncthreads();
    int base = blockIdx.x * 8192;
    for (int k = threadIdx.x; k < 8192; k += 256) {
        int e = base + k;
        if (e < ETOT) {
            int dst = (e < EE) ? ei[EE + e] : (e - EE);
            atomicAdd(&cnt[dst >> 8], 1);
        }
    }
    __syncthreads();
    for (int i = threadIdx.x; i < NBK; i += 256)
        if (cnt[i]) atomicAdd(&bucket_cnt[i], cnt[i]);
}

// also plants the -inf esrc sentinel used by pad edges (src = NN)
__global__ __launch_bounds__(512) void bucket_scan_kernel(
    const int* __restrict__ bucket_cnt, int* __restrict__ bucket_base,
    int* __restrict__ gcursor, float* __restrict__ esrcs)
{
    __shared__ int s[512];
    int t = threadIdx.x;
    int v = (t < NBK) ? bucket_cnt[t] : 0;
    s[t] = v;
    __syncthreads();
    int x = v;
    for (int o = 1; o < 512; o <<= 1) {
        int y = (t >= o) ? s[t - o] : 0;
        __syncthreads();
        x += y;
        s[t] = x;
        __syncthreads();
    }
    if (t < NBK) { bucket_base[t] = x - v; gcursor[t] = x - v; }
    if (t == 0) {
        bucket_base[NBK] = ETOT;
        esrcs[2 * NN]     = __int_as_float(0xFF800000);  // -inf
        esrcs[2 * NN + 1] = __int_as_float(0xFF800000);
    }
}

__global__ __launch_bounds__(256) void partition_kernel(
    const int* __restrict__ ei, int* __restrict__ gcursor, int* __restrict__ part)
{
    __shared__ int cnt[NBK];
    __shared__ int basel[NBK];
    for (int i = threadIdx.x; i < NBK; i += 256) cnt[i] = 0;
    __syncthreads();
    int base = blockIdx.x * 4096;
    for (int k = threadIdx.x; k < 4096; k += 256) {
        int e = base + k;
        if (e < ETOT) {
            int dst = (e < EE) ? ei[EE + e] : (e - EE);
            atomicAdd(&cnt[dst >> 8], 1);
        }
    }
    __syncthreads();
    for (int i = threadIdx.x; i < NBK; i += 256) {
        int c = cnt[i];
        basel[i] = c ? atomicAdd(&gcursor[i], c) : 0;
        cnt[i] = 0;   // reuse as intra-block cursor
    }
    __syncthreads();
    for (int k = threadIdx.x; k < 4096; k += 256) {
        int e = base + k;
        if (e < ETOT) {
            int src, dst;
            if (e < EE) { src = ei[e]; dst = ei[EE + e]; }
            else        { src = e - EE; dst = e - EE; }
            int b = dst >> 8;
            int slot = atomicAdd(&cnt[b], 1);
            part[basel[b] + slot] = src | ((dst & 255) << 17);
        }
    }
}

// Padded CSR: per-node segments rounded up to 8 entries (pad-8, R3 win).
// Pad src = NN (sentinel: esrc[NN] = -inf → exp weight 0).
__global__ __launch_bounds__(256) void csr_build_kernel(
    const int* __restrict__ part, const int* __restrict__ bucket_base,
    int* __restrict__ row2_start, int* __restrict__ row2_deg,
    int* __restrict__ csr2_src)
{
    __shared__ int degs[256];
    __shared__ int sc[256];
    __shared__ int cur[256];
    int b = blockIdx.x;
    int t = threadIdx.x;
    int beg = bucket_base[b], end = bucket_base[b + 1];
    int pbase = ((beg + 7) & ~7) + 4096 * b;
    degs[t] = 0;
    __syncthreads();
    for (int j = beg + t; j < end; j += 256)
        atomicAdd(&degs[(part[j] >> 17) & 255], 1);
    __syncthreads();
    int dg = degs[t];
    int pdeg = (dg + 7) & ~7;
    sc[t] = pdeg;
    __syncthreads();
    int x = pdeg;
    for (int o = 1; o < 256; o <<= 1) {
        int y = (t >= o) ? sc[t - o] : 0;
        __syncthreads();
        x += y;
        sc[t] = x;
        __syncthreads();
    }
    int start2 = pbase + (x - pdeg);
    int node = b * 256 + t;
    if (node < NN) { row2_start[node] = start2; row2_deg[node] = dg; }
    cur[t] = start2;
    __syncthreads();
    for (int j = beg + t; j < end; j += 256) {
        int pv = part[j];
        int pos = atomicAdd(&cur[(pv >> 17) & 255], 1);
        csr2_src[pos] = pv & 0x1FFFF;
    }
    for (int k = dg; k < pdeg; ++k) csr2_src[start2 + k] = NN;
}

// ---------------- merged prep: W-fragments (both layers) + fused BN ----------

template<int K>
__device__ __forceinline__ void prep_w_body(
    int unit, const float* __restrict__ W, const float* __restrict__ pw,
    short* __restrict__ wfrag)
{
    constexpr int KS = K / 32;
    int total = 16 * KS * 2 * 64;
    if (unit >= total) return;
    int lane = unit & 63;
    int rest = unit >> 6;
    int hilo = rest & 1;
    int fk = rest >> 1;
    int ks = fk % KS;
    int nt = fk / KS;
    int n = nt * 16 + (lane & 15);
    int k0 = ks * 32 + (lane >> 4) * 8;
    const float* src = (n < 128) ? (W + n) : (pw + (n - 128));
    s16x8 out;
#pragma unroll
    for (int j = 0; j < 8; ++j) {
        float wv = src[(size_t)(k0 + j) * 128];
        unsigned short hi = f2bf(wv);
        if (hilo == 0) {
            out[j] = (short)hi;
        } else {
            float fhi = __uint_as_float(((unsigned)hi) << 16);
            out[j] = (short)f2bf(wv - fhi);
        }
    }
    *(s16x8*)(wfrag + (size_t)unit * 8) = out;
}

__global__ __launch_bounds__(256) void prep_all_kernel(
    const float* __restrict__ w2, const float* __restrict__ p2w, short* __restrict__ wfrag2,
    const float* __restrict__ w3, const float* __restrict__ p3w, short* __restrict__ wfrag3,
    const float* b1, const float* g1, const float* be1, const float* m1, const float* v1,
    const float* b2, const float* g2, const float* be2, const float* m2, const float* v2,
    const float* b3, const float* g3, const float* be3, const float* m3, const float* v3,
    float* sc1, float* sh1, float* sc2, float* sh2, float* sc3, float* sh3)
{
    int b = blockIdx.x;
    int tid = threadIdx.x;
    if (b < 16) {
        prep_w_body<64>(b * 256 + tid, w2, p2w, wfrag2);
    } else if (b < 48) {
        prep_w_body<128>((b - 16) * 256 + tid, w3, p3w, wfrag3);
    } else {
        int t = tid;
        if (t < 128) {
            if (t < 64) {
                float sc = g1[t] * rsqrtf(v1[t] + BNEPS);
                sc1[t] = sc;
                sh1[t] = (b1[t] - m1[t]) * sc + be1[t];
            }
            {
                float sc = g2[t] * rsqrtf(v2[t] + BNEPS);
                sc2[t] = sc;
                sh2[t] = (b2[t] - m2[t]) * sc + be2[t];
            }
            {
                float sc = g3[t] * rsqrtf(v3[t] + BNEPS);
                sc3[t] = sc;
                sh3[t] = (b3[t] - m3[t]) * sc + be3[t];
            }
        }
    }
}

// ---------------- per-layer edge softmax weights (packed 2×bf16) -------------
// R8: 2 nodes/wave (32 lanes each) — mean padded degree ~21 left 2/3 of a
// 64-lane wave idle per node.

__global__ __launch_bounds__(256) void edgew_kernel(
    const int* __restrict__ csr2_src, const int* __restrict__ row2_start,
    const int* __restrict__ row2_deg,
    const float2* __restrict__ esrc, const float2* __restrict__ edst,
    unsigned* __restrict__ csr_w, int nN)
{
    int n = blockIdx.x * 8 + (threadIdx.x >> 5);
    int hl = threadIdx.x & 31;
    if (n >= nN) return;
    float2 ed = edst[n];
    int s2 = row2_start[n];
    int dg = row2_deg[n];
    int pc = (dg + 7) & ~7;
    for (int j = hl; j < pc; j += 32) {
        int i = csr2_src[s2 + j];
        float2 es = esrc[i];
        float a0 = es.x + ed.x; a0 = (a0 > 0.f) ? a0 : 0.2f * a0;
        float a1 = es.y + ed.y; a1 = (a1 > 0.f) ? a1 : 0.2f * a1;
        unsigned w = (unsigned)f2bf(__expf(a0)) | ((unsigned)f2bf(__expf(a1)) << 16);
        csr_w[s2 + j] = w;
    }
}

// ---------------- layer-1 feature transform (K=5); h fp8, rout bf16 ----------

__global__ __launch_bounds__(256) void feat1_kernel(
    const float* __restrict__ xin, const float* __restrict__ W,
    const float* __restrict__ pw, const float* __restrict__ pb,
    const float* __restrict__ a_src, const float* __restrict__ a_dst,
    unsigned char* __restrict__ h8, float* __restrict__ esrc, float* __restrict__ edst,
    unsigned short* __restrict__ rout16, int nN)
{
    constexpr int F_IN = 5, F_OUT = 64;
    int t = threadIdx.x;
    int n = blockIdx.x * 4 + t / F_OUT;
    int f = t % F_OUT;
    if (n >= nN) return;
    float acc = 0.f, racc = 0.f;
#pragma unroll
    for (int k = 0; k < F_IN; ++k) {
        float xv = xin[n * F_IN + k];
        acc  += xv * W[k * F_OUT + f];
        racc += xv * pw[k * F_OUT + f];
    }
    float other = __shfl_xor(acc, 1, 64);
    if ((f & 1) == 0) {
        int p = __builtin_amdgcn_cvt_pk_fp8_f32(acc, other, 0, false);
        *(unsigned short*)(h8 + (size_t)n * F_OUT + f) = (unsigned short)(p & 0xFFFF);
    }
    rout16[(size_t)n * F_OUT + f] = f2bf(racc + pb[f]);
    float es = acc * a_src[f];
    float ed = acc * a_dst[f];
#pragma unroll
    for (int off = 16; off > 0; off >>= 1) {
        es += __shfl_xor(es, off, 32);
        ed += __shfl_xor(ed, off, 32);
    }
    if ((t & 31) == 0) {
        int head = (f >> 5) & 1;
        esrc[n * 2 + head] = es;
        edst[n * 2 + head] = ed;
    }
}

// ---------------- MFMA feature transform (layers 2,3; N=256 = W‖pw) ----------
// R7 WIN: column-split dataflow — each wave owns 2 nt-columns, b-frags loaded
// once into registers, rows stream from LDS. Kept unchanged in R8.

template<int K>
__global__ __launch_bounds__(512, 4) void mfma_feat_kernel(
    const unsigned short* __restrict__ xin16, const short* __restrict__ wfrag,
    const float* __restrict__ pb,
    const float* __restrict__ a_src, const float* __restrict__ a_dst,
    unsigned char* __restrict__ h8, float* __restrict__ esrc, float* __restrict__ edst,
    unsigned short* __restrict__ rout16)
{
    constexpr int KS = K / 32;    // MFMA k-steps
    constexpr int CH = K / 8;     // 8-feature (16 B) chunks per node row
    __shared__ __align__(16) char smem[1024 * CH + 28672];
    s16x8* xs = (s16x8*)smem;                                              // [4][CH][16] tiles
    unsigned short* h8lds = (unsigned short*)(smem + 1024 * CH);           // [64][72]
    unsigned short* rolds = (unsigned short*)(smem + 1024 * CH + 9216);    // [64][136]
    float2* espart = (float2*)(smem + 1024 * CH + 26624);                  // [4][64] {es,ed}

    const int tid = threadIdx.x;
    const int base = blockIdx.x * 64;

    for (int idx = tid; idx < 64 * CH; idx += 512) {
        int node = idx / CH;
        int ch = idx % CH;
        int gn = base + node; if (gn > NN - 1) gn = NN - 1;
        s16x8 v = *(const s16x8*)(xin16 + (size_t)gn * K + ch * 8);
        int tt = node >> 4, mm = node & 15;
        xs[(tt * CH + ch) * 16 + mm] = v;
    }
    __syncthreads();

    const int w = tid >> 6;             // 0..7: column-pair owner
    const int lane = tid & 63;
    const int quad = lane >> 4;
    const int m = lane & 15;
    const int nt0 = 2 * w, nt1 = nt0 + 1;

    // b-fragments for this wave's two output columns: loaded ONCE.
    s16x8 bA[2 * KS], bB[2 * KS];
#pragma unroll
    for (int i = 0; i < 2 * KS; ++i) {
        bA[i] = *(const s16x8*)(wfrag + (size_t)((nt0 * KS * 2 + i) * 64 + lane) * 8);
        bB[i] = *(const s16x8*)(wfrag + (size_t)((nt1 * KS * 2 + i) * 64 + lane) * 8);
    }

    const bool hpart = (w < 4);
    float av0 = 0.f, dv0 = 0.f, av1 = 0.f, dv1 = 0.f, bv0 = 0.f, bv1 = 0.f;
    if (hpart) {
        av0 = a_src[nt0 * 16 + m]; dv0 = a_dst[nt0 * 16 + m];
        av1 = a_src[nt1 * 16 + m]; dv1 = a_dst[nt1 * 16 + m];
    } else {
        bv0 = pb[(nt0 - 8) * 16 + m]; bv1 = pb[(nt1 - 8) * 16 + m];
    }

#pragma unroll
    for (int rt = 0; rt < 4; ++rt) {
        s16x8 a[KS];
#pragma unroll
        for (int ks = 0; ks < KS; ++ks)
            a[ks] = xs[(rt * CH + ks * 4 + quad) * 16 + m];
        f32x4v cA = {0.f, 0.f, 0.f, 0.f};
        f32x4v cB = {0.f, 0.f, 0.f, 0.f};
#pragma unroll
        for (int ks = 0; ks < KS; ++ks) {
            cA = __builtin_amdgcn_mfma_f32_16x16x32_bf16(a[ks], bA[2 * ks + 0], cA, 0, 0, 0);
            cA = __builtin_amdgcn_mfma_f32_16x16x32_bf16(a[ks], bA[2 * ks + 1], cA, 0, 0, 0);
            cB = __builtin_amdgcn_mfma_f32_16x16x32_bf16(a[ks], bB[2 * ks + 0], cB, 0, 0, 0);
            cB = __builtin_amdgcn_mfma_f32_16x16x32_bf16(a[ks], bB[2 * ks + 1], cB, 0, 0, 0);
        }
        int row0 = rt * 16 + quad * 4;
        if (hpart) {
#pragma unroll
            for (int r = 0; r < 4; ++r) {
                float v0 = cA[r], v1 = cB[r];
                float es = v0 * av0 + v1 * av1;
                float ed = v0 * dv0 + v1 * dv1;
#pragma unroll
                for (int off = 8; off > 0; off >>= 1) {
                    es += __shfl_xor(es, off, 16);
                    ed += __shfl_xor(ed, off, 16);
                }
                if (m == 0) espart[w * 64 + row0 + r] = make_float2(es, ed);
                float p0 = __shfl_xor(v0, 1, 16);
                float p1 = __shfl_xor(v1, 1, 16);
                if ((m & 1) == 0) {
                    int pk0 = __builtin_amdgcn_cvt_pk_fp8_f32(v0, p0, 0, false);
                    int pk1 = __builtin_amdgcn_cvt_pk_fp8_f32(v1, p1, 0, false);
                    h8lds[(row0 + r) * 72 + nt0 * 8 + (m >> 1)] = (unsigned short)(pk0 & 0xFFFF);
                    h8lds[(row0 + r) * 72 + nt1 * 8 + (m >> 1)] = (unsigned short)(pk1 & 0xFFFF);
                }
            }
        } else {
#pragma unroll
            for (int r = 0; r < 4; ++r) {
                rolds[(row0 + r) * 136 + (nt0 - 8) * 16 + m] = f2bf(cA[r] + bv0);
                rolds[(row0 + r) * 136 + (nt1 - 8) * 16 + m] = f2bf(cB[r] + bv1);
            }
        }
    }

    __syncthreads();

    // es/ed cross-wave reduce: head0 = waves 0,1 (cols 0..63); head1 = waves 2,3.
    if (tid < 64) {
        int node = base + tid;
        if (node < NN) {
            float2 e0 = espart[0 * 64 + tid];
            float2 e1 = espart[1 * 64 + tid];
            float2 e2 = espart[2 * 64 + tid];
            float2 e3 = espart[3 * 64 + tid];
            ((float2*)esrc)[node] = make_float2(e0.x + e1.x, e2.x + e3.x);
            ((float2*)edst)[node] = make_float2(e0.y + e1.y, e2.y + e3.y);
        }
    }
    for (int i = tid; i < 64 * 8; i += 512) {
        int row = i >> 3, ch = i & 7;
        int node = base + row;
        if (node < NN) {
            int4 v = *(const int4*)((char*)h8lds + row * 144 + ch * 16);
            *(int4*)(h8 + (size_t)node * 128 + ch * 16) = v;
        }
    }
    for (int i = tid; i < 64 * 16; i += 512) {
        int row = i >> 4, ch = i & 15;
        int node = base + row;
        if (node < NN) {
            int4 v = *(const int4*)((char*)rolds + row * 272 + ch * 16);
            *(int4*)((char*)rout16 + (size_t)node * 256 + ch * 16) = v;
        }
    }
}

// ---------------- fused aggregate, F=128 (persistent grid-stride waves) ------
// R8: grid = 2048 blocks (8/CU, exactly 32 waves/CU at VGPR 32). Each wave
// iterates ~6 node-pairs — removes block churn, lets next pair's CSR loads
// overlap current pair's pkfma chain.

__global__ __launch_bounds__(256) void aggregate128_kernel(
    const unsigned char* __restrict__ h8,
    const int* __restrict__ row2_start, const int* __restrict__ row2_deg,
    const int* __restrict__ csr2_src, const unsigned* __restrict__ csr_w,
    const float* __restrict__ bnsc, const float* __restrict__ bnsh,
    unsigned short* __restrict__ io16)
{
    int w = threadIdx.x >> 6;
    int lane = threadIdx.x & 63;
    int half = lane >> 5;
    int fl = lane & 31;               // dword within the 128 B row (4 features)
    unsigned shl = (fl >= 16) ? 0u : 16u;   // head1 keeps hi bf16, head0 shifts up
    int gw = blockIdx.x * 4 + w;
    const int NWAVES = 2048 * 4;
    for (int np = gw; np < NN / 2; np += NWAVES) {
        int n = np * 2 + half;
        int s2 = row2_start[n];
        int dg = row2_deg[n];
        int pc = (dg + 7) & ~7;
        const int4* sp = (const int4*)(csr2_src + s2);
        const uint4* wp = (const uint4*)(csr_w + s2);
        float s = 0.f;
        floatx2 acc01 = {0.f, 0.f}, acc23 = {0.f, 0.f};
        for (int j = 0; j < pc; j += 8) {
            int4 ia = sp[(j >> 2) + 0];
            int4 ib = sp[(j >> 2) + 1];
            uint4 wa = wp[(j >> 2) + 0];
            uint4 wb = wp[(j >> 2) + 1];
            unsigned d0 = *(const unsigned*)(h8 + (size_t)ia.x * 128 + fl * 4);
            unsigned d1 = *(const unsigned*)(h8 + (size_t)ia.y * 128 + fl * 4);
            unsigned d2 = *(const unsigned*)(h8 + (size_t)ia.z * 128 + fl * 4);
            unsigned d3 = *(const unsigned*)(h8 + (size_t)ia.w * 128 + fl * 4);
            unsigned d4 = *(const unsigned*)(h8 + (size_t)ib.x * 128 + fl * 4);
            unsigned d5 = *(const unsigned*)(h8 + (size_t)ib.y * 128 + fl * 4);
            unsigned d6 = *(const unsigned*)(h8 + (size_t)ib.z * 128 + fl * 4);
            unsigned d7 = *(const unsigned*)(h8 + (size_t)ib.w * 128 + fl * 4);
            float g0 = __uint_as_float((wa.x << shl) & 0xFFFF0000u);
            float g1 = __uint_as_float((wa.y << shl) & 0xFFFF0000u);
            float g2 = __uint_as_float((wa.z << shl) & 0xFFFF0000u);
            float g3 = __uint_as_float((wa.w << shl) & 0xFFFF0000u);
            float g4 = __uint_as_float((wb.x << shl) & 0xFFFF0000u);
            float g5 = __uint_as_float((wb.y << shl) & 0xFFFF0000u);
            float g6 = __uint_as_float((wb.z << shl) & 0xFFFF0000u);
            float g7 = __uint_as_float((wb.w << shl) & 0xFFFF0000u);
            floatx2 gv0 = {g0, g0};
            floatx2 gv1 = {g1, g1};
            floatx2 gv2 = {g2, g2};
            floatx2 gv3 = {g3, g3};
            floatx2 gv4 = {g4, g4};
            floatx2 gv5 = {g5, g5};
            floatx2 gv6 = {g6, g6};
            floatx2 gv7 = {g7, g7};
            acc01 = pkfma(gv0, __builtin_amdgcn_cvt_pk_f32_fp8((int)d0, false), acc01);
            acc23 = pkfma(gv0, __builtin_amdgcn_cvt_pk_f32_fp8((int)d0, true),  acc23);
            acc01 = pkfma(gv1, __builtin_amdgcn_cvt_pk_f32_fp8((int)d1, false), acc01);
            acc23 = pkfma(gv1, __builtin_amdgcn_cvt_pk_f32_fp8((int)d1, true),  acc23);
            acc01 = pkfma(gv2, __builtin_amdgcn_cvt_pk_f32_fp8((int)d2, false), acc01);
            acc23 = pkfma(gv2, __builtin_amdgcn_cvt_pk_f32_fp8((int)d2, true),  acc23);
            acc01 = pkfma(gv3, __builtin_amdgcn_cvt_pk_f32_fp8((int)d3, false), acc01);
            acc23 = pkfma(gv3, __builtin_amdgcn_cvt_pk_f32_fp8((int)d3, true),  acc23);
            acc01 = pkfma(gv4, __builtin_amdgcn_cvt_pk_f32_fp8((int)d4, false), acc01);
            acc23 = pkfma(gv4, __builtin_amdgcn_cvt_pk_f32_fp8((int)d4, true),  acc23);
            acc01 = pkfma(gv5, __builtin_amdgcn_cvt_pk_f32_fp8((int)d5, false), acc01);
            acc23 = pkfma(gv5, __builtin_amdgcn_cvt_pk_f32_fp8((int)d5, true),  acc23);
            acc01 = pkfma(gv6, __builtin_amdgcn_cvt_pk_f32_fp8((int)d6, false), acc01);
            acc23 = pkfma(gv6, __builtin_amdgcn_cvt_pk_f32_fp8((int)d6, true),  acc23);
            acc01 = pkfma(gv7, __builtin_amdgcn_cvt_pk_f32_fp8((int)d7, false), acc01);
            acc23 = pkfma(gv7, __builtin_amdgcn_cvt_pk_f32_fp8((int)d7, true),  acc23);
            s += (((g0 + g1) + (g2 + g3)) + ((g4 + g5) + (g6 + g7)));
        }
        float inv = 1.f / (s + 1e-16f);
        int f0 = fl * 4;
        float4 sc = *(const float4*)(bnsc + f0);
        float4 sh = *(const float4*)(bnsh + f0);
        float o0 = fmaf(acc01.x * inv, sc.x, sh.x);
        float o1 = fmaf(acc01.y * inv, sc.y, sh.y);
        float o2 = fmaf(acc23.x * inv, sc.z, sh.z);
        float o3 = fmaf(acc23.y * inv, sc.w, sh.w);
        uint2* iop = (uint2*)(io16 + (size_t)n * 128 + f0);
        uint2 pu = *iop;
        float r0 = fmaxf(o0, 0.f) + __uint_as_float((pu.x & 0xFFFFu) << 16);
        float r1 = fmaxf(o1, 0.f) + __uint_as_float(pu.x & 0xFFFF0000u);
        float r2 = fmaxf(o2, 0.f) + __uint_as_float((pu.y & 0xFFFFu) << 16);
        float r3 = fmaxf(o3, 0.f) + __uint_as_float(pu.y & 0xFFFF0000u);
        uint2 ov;
        ov.x = (unsigned)f2bf(r0) | ((unsigned)f2bf(r1) << 16);
        ov.y = (unsigned)f2bf(r2) | ((unsigned)f2bf(r3) << 16);
        *iop = ov;
    }
}

// ---------------- fused aggregate, F=64 (two nodes/wave, pk_fma) -------------

__global__ __launch_bounds__(256) void aggregate64_kernel(
    const unsigned char* __restrict__ h8,
    const int* __restrict__ row2_start, const int* __restrict__ row2_deg,
    const int* __restrict__ csr2_src, const unsigned* __restrict__ csr_w,
    const float* __restrict__ bnsc, const float* __restrict__ bnsh,
    unsigned short* __restrict__ io16)
{
    int w = threadIdx.x >> 6;
    int lane = threadIdx.x & 63;
    int half = lane >> 5;
    int hl = lane & 31;
    int q  = hl >> 4;                 // edge selector within pair
    int fl = hl & 15;                 // feature dword (features 4fl..4fl+3)
    unsigned shl = (fl >= 8) ? 0u : 16u;
    int n = blockIdx.x * 8 + w * 2 + half;
    int s2 = row2_start[n];
    int dg = row2_deg[n];
    int pc = (dg + 7) & ~7;
    const int4* sp = (const int4*)(csr2_src + s2);
    const uint4* wp = (const uint4*)(csr_w + s2);
    float s = 0.f;
    floatx2 acc01 = {0.f, 0.f}, acc23 = {0.f, 0.f};
    for (int j = 0; j < pc; j += 8) {
        int4 ia = sp[(j >> 2) + 0];
        int4 ib = sp[(j >> 2) + 1];
        uint4 wa = wp[(j >> 2) + 0];
        uint4 wb = wp[(j >> 2) + 1];
        int i0 = q ? ia.y : ia.x;
        int i1 = q ? ia.w : ia.z;
        int i2 = q ? ib.y : ib.x;
        int i3 = q ? ib.w : ib.z;
        unsigned w0 = q ? wa.y : wa.x;
        unsigned w1 = q ? wa.w : wa.z;
        unsigned w2 = q ? wb.y : wb.x;
        unsigned w3 = q ? wb.w : wb.z;
        unsigned d0 = *(const unsigned*)(h8 + (size_t)i0 * 64 + fl * 4);
        unsigned d1 = *(const unsigned*)(h8 + (size_t)i1 * 64 + fl * 4);
        unsigned d2 = *(const unsigned*)(h8 + (size_t)i2 * 64 + fl * 4);
        unsigned d3 = *(const unsigned*)(h8 + (size_t)i3 * 64 + fl * 4);
        float g0 = __uint_as_float((w0 << shl) & 0xFFFF0000u);
        float g1 = __uint_as_float((w1 << shl) & 0xFFFF0000u);
        float g2 = __uint_as_float((w2 << shl) & 0xFFFF0000u);
        float g3 = __uint_as_float((w3 << shl) & 0xFFFF0000u);
        floatx2 gv0 = {g0, g0};
        floatx2 gv1 = {g1, g1};
        floatx2 gv2 = {g2, g2};
        floatx2 gv3 = {g3, g3};
        acc01 = pkfma(gv0, __builtin_amdgcn_cvt_pk_f32_fp8((int)d0, false), acc01);
        acc23 = pkfma(gv0, __builtin_amdgcn_cvt_pk_f32_fp8((int)d0, true),  acc23);
        acc01 = pkfma(gv1, __builtin_amdgcn_cvt_pk_f32_fp8((int)d1, false), acc01);
        acc23 = pkfma(gv1, __builtin_amdgcn_cvt_pk_f32_fp8((int)d1, true),  acc23);
        acc01 = pkfma(gv2, __builtin_amdgcn_cvt_pk_f32_fp8((int)d2, false), acc01);
        acc23 = pkfma(gv2, __builtin_amdgcn_cvt_pk_f32_fp8((int)d2, true),  acc23);
        acc01 = pkfma(gv3, __builtin_amdgcn_cvt_pk_f32_fp8((int)d3, false), acc01);
        acc23 = pkfma(gv3, __builtin_amdgcn_cvt_pk_f32_fp8((int)d3, true),  acc23);
        s += ((g0 + g1) + (g2 + g3));
    }
    // combine the two quarters within each half (xor 16 stays inside the half)
    acc01.x += __shfl_xor(acc01.x, 16);
    acc01.y += __shfl_xor(acc01.y, 16);
    acc23.x += __shfl_xor(acc23.x, 16);
    acc23.y += __shfl_xor(acc23.y, 16);
    s += __shfl_xor(s, 16);
    if (hl < 16) {
        float inv = 1.f / (s + 1e-16f);
        int f0 = fl * 4;
        float4 sc = *(const float4*)(bnsc + f0);
        float4 sh = *(const float4*)(bnsh + f0);
        float o0 = fmaf(acc01.x * inv, sc.x, sh.x);
        float o1 = fmaf(acc01.y * inv, sc.y, sh.y);
        float o2 = fmaf(acc23.x * inv, sc.z, sh.z);
        float o3 = fmaf(acc23.y * inv, sc.w, sh.w);
        uint2* iop = (uint2*)(io16 + (size_t)n * 64 + f0);
        uint2 pu = *iop;
        float r0 = fmaxf(o0, 0.f) + __uint_as_float((pu.x & 0xFFFFu) << 16);
        float r1 = fmaxf(o1, 0.f) + __uint_as_float(pu.x & 0xFFFF0000u);
        float r2 = fmaxf(o2, 0.f) + __uint_as_float((pu.y & 0xFFFFu) << 16);
        float r3 = fmaxf(o3, 0.f) + __uint_as_float(pu.y & 0xFFFF0000u);
        uint2 ov;
        ov.x = (unsigned)f2bf(r0) | ((unsigned)f2bf(r1) << 16);
        ov.y = (unsigned)f2bf(r2) | ((unsigned)f2bf(r3) << 16);
        *iop = ov;
    }
}

// ---------------- pooling, two-phase (bf16 input) ----------------

__global__ __launch_bounds__(128) void pool_partial_kernel(
    const unsigned short* __restrict__ hf16, const int* __restrict__ batch,
    float* __restrict__ ppart)
{
    int g = blockIdx.x / PSPLIT;
    int p = blockIdx.x % PSPLIT;
    int f = threadIdx.x;
    int lo = 0, hi = NN;
    while (lo < hi) { int mid = (lo + hi) >> 1; if (batch[mid] < g) lo = mid + 1; else hi = mid; }
    int start = lo;
    hi = NN;
    while (lo < hi) { int mid = (lo + hi) >> 1; if (batch[mid] < g + 1) lo = mid + 1; else hi = mid; }
    int end = lo;
    int len = end - start;
    int chunk = (len + PSPLIT - 1) / PSPLIT;
    int i0 = start + p * chunk;
    int i1 = i0 + chunk; if (i1 > end) i1 = end;
    float acc = 0.f;
    for (int i = i0; i < i1; ++i) acc += bf2f(hf16[(size_t)i * 128 + f]);
    ppart[((size_t)g * PSPLIT + p) * 128 + f] = acc;
}

// ---------------- MLP head (folds partial-sum reduce + mean) -----------------

__global__ __launch_bounds__(128) void head_kernel(
    const float* __restrict__ ppart, const int* __restrict__ batch,
    const float* __restrict__ fw, const float* __restrict__ fb,
    const float* __restrict__ g4, const float* __restrict__ be4,
    const float* __restrict__ m4, const float* __restrict__ v4,
    const float* __restrict__ l1w, const float* __restrict__ l1b,
    const float* __restrict__ l2w, const float* __restrict__ l2b,
    float* __restrict__ out)
{
    __shared__ float p[128];
    __shared__ float z1[32];
    __shared__ float z2[32];
    int g = blockIdx.x, t = threadIdx.x;
    int lo = 0, hi = NN;
    while (lo < hi) { int mid = (lo + hi) >> 1; if (batch[mid] < g) lo = mid + 1; else hi = mid; }
    int start = lo;
    hi = NN;
    while (lo < hi) { int mid = (lo + hi) >> 1; if (batch[mid] < g + 1) lo = mid + 1; else hi = mid; }
    float cnt = (float)(lo - start);
    float acc = 0.f;
#pragma unroll
    for (int q = 0; q < PSPLIT; ++q)
        acc += ppart[((size_t)g * PSPLIT + q) * 128 + t];
    p[t] = acc / fmaxf(cnt, 1.0f);
    __syncthreads();
    if (t < 32) {
        float a = fb[t];
        for (int k = 0; k < 128; ++k) a += p[k] * fw[k * 32 + t];
        float val = g4[t] * (a - m4[t]) * rsqrtf(v4[t] + BNEPS) + be4[t];
        z1[t] = fmaxf(val, 0.f);
    }
    __syncthreads();
    if (t < 32) {
        float a = l1b[t];
        for (int k = 0; k < 32; ++k) a += z1[k] * l1w[k * 32 + t];
        z2[t] = fmaxf(a, 0.f);
    }
    __syncthreads();
    if (t < 10) {
        float a = l2b[t];
        for (int k = 0; k < 32; ++k) a += z2[k] * l2w[k * 10 + t];
        out[g * 10 + t] = a;
    }
}

// ---------------- launch ----------------

extern "C" void kernel_launch(void* const* d_in, const int* in_sizes, int n_in,
                              void* d_out, int out_size, void* d_ws, size_t ws_size,
                              hipStream_t stream) {
    const float* x     = (const float*)d_in[0];
    const int*   ei    = (const int*)d_in[1];
    const int*   batch = (const int*)d_in[2];
    const float* w1  = (const float*)d_in[3];
    const float* as1 = (const float*)d_in[4];
    const float* ad1 = (const float*)d_in[5];
    const float* b1  = (const float*)d_in[6];
    const float* g1  = (const float*)d_in[7];
    const float* be1 = (const float*)d_in[8];
    const float* m1  = (const float*)d_in[9];
    const float* v1  = (const float*)d_in[10];
    const float* p1w = (const float*)d_in[11];
    const float* p1b = (const float*)d_in[12];
    const float* w2  = (const float*)d_in[13];
    const float* as2 = (const float*)d_in[14];
    const float* ad2 = (const float*)d_in[15];
    const float* b2  = (const float*)d_in[16];
    const float* g2  = (const float*)d_in[17];
    const float* be2 = (const float*)d_in[18];
    const float* m2  = (const float*)d_in[19];
    const float* v2  = (const float*)d_in[20];
    const float* p2w = (const float*)d_in[21];
    const float* p2b = (const float*)d_in[22];
    const float* w3  = (const float*)d_in[23];
    const float* as3 = (const float*)d_in[24];
    const float* ad3 = (const float*)d_in[25];
    const float* b3  = (const float*)d_in[26];
    const float* g3  = (const float*)d_in[27];
    const float* be3 = (const float*)d_in[28];
    const float* m3  = (const float*)d_in[29];
    const float* v3  = (const float*)d_in[30];
    const float* p3w = (const float*)d_in[31];
    const float* p3b = (const float*)d_in[32];
    const float* fw  = (const float*)d_in[33];
    const float* fb  = (const float*)d_in[34];
    const float* g4  = (const float*)d_in[35];
    const float* be4 = (const float*)d_in[36];
    const float* m4  = (const float*)d_in[37];
    const float* v4  = (const float*)d_in[38];
    const float* l1w = (const float*)d_in[39];
    const float* l1b = (const float*)d_in[40];
    const float* l2w = (const float*)d_in[41];
    const float* l2b = (const float*)d_in[42];

    char* ws = (char*)d_ws;
    size_t off = 0;
    auto alloc = [&](size_t bytes) -> char* {
        char* p = ws + off;
        off += (bytes + 255) & ~(size_t)255;
        return p;
    };
    int*    bucket_cnt  = (int*)alloc((NBK) * sizeof(int));
    int*    bucket_base = (int*)alloc((NBK + 1) * sizeof(int));
    int*    gcursor     = (int*)alloc((NBK) * sizeof(int));
    int*    part        = (int*)alloc((size_t)ETOT * sizeof(int));
    int*    row2_start  = (int*)alloc(NN * sizeof(int));
    int*    row2_deg    = (int*)alloc(NN * sizeof(int));
    int*    csr2_src    = (int*)alloc((size_t)PADTOT * sizeof(int));
    unsigned* csr_w     = (unsigned*)alloc((size_t)PADTOT * sizeof(unsigned));
    unsigned char*  h8  = (unsigned char*)alloc((size_t)(NN + 1) * 128);
    unsigned short* hb1 = (unsigned short*)alloc((size_t)NN * 64 * sizeof(short));
    unsigned short* hb2 = (unsigned short*)alloc((size_t)NN * 128 * sizeof(short));
    unsigned short* hb3 = (unsigned short*)alloc((size_t)NN * 128 * sizeof(short));
    float*  esrc        = (float*)alloc((size_t)(NN + 1) * 2 * sizeof(float));
    float*  edst        = (float*)alloc((size_t)NN * 2 * sizeof(float));
    float*  ppart       = (float*)alloc((size_t)GG * PSPLIT * 128 * sizeof(float));
    short*  wfrag2      = (short*)alloc((size_t)16 * 2 * 2 * 64 * 8 * sizeof(short));
    short*  wfrag3      = (short*)alloc((size_t)16 * 4 * 2 * 64 * 8 * sizeof(short));
    float*  bnsc1       = (float*)alloc(64 * sizeof(float));
    float*  bnsh1       = (float*)alloc(64 * sizeof(float));
    float*  bnsc2       = (float*)alloc(128 * sizeof(float));
    float*  bnsh2       = (float*)alloc(128 * sizeof(float));
    float*  bnsc3       = (float*)alloc(128 * sizeof(float));
    float*  bnsh3       = (float*)alloc(128 * sizeof(float));

    // ---- merged prep (W fragments + fused BN) ----
    prep_all_kernel<<<49, 256, 0, stream>>>(
        w2, p2w, wfrag2, w3, p3w, wfrag3,
        b1, g1, be1, m1, v1, b2, g2, be2, m2, v2, b3, g3, be3, m3, v3,
        bnsc1, bnsh1, bnsc2, bnsh2, bnsc3, bnsh3);

    // ---- CSR build (bucketed partition, padded-8 layout, NN sentinel) ----
    hipMemsetAsync(bucket_cnt, 0, NBK * sizeof(int), stream);
    bucket_count_kernel<<<(ETOT + 8191) / 8192, 256, 0, stream>>>(ei, bucket_cnt);
    bucket_scan_kernel<<<1, 512, 0, stream>>>(bucket_cnt, bucket_base, gcursor, esrc);
    partition_kernel<<<(ETOT + 4095) / 4096, 256, 0, stream>>>(ei, gcursor, part);
    csr_build_kernel<<<NBK, 256, 0, stream>>>(part, bucket_base, row2_start, row2_deg, csr2_src);

    // ---- layer 1: x[N,5] -> hb1[N,64] (bf16) ----
    feat1_kernel<<<(NN + 3) / 4, 256, 0, stream>>>(
        x, w1, p1w, p1b, as1, ad1, h8, esrc, edst, hb1, NN);
    edgew_kernel<<<(NN + 7) / 8, 256, 0, stream>>>(
        csr2_src, row2_start, row2_deg, (const float2*)esrc, (const float2*)edst, csr_w, NN);
    aggregate64_kernel<<<NN / 8, 256, 0, stream>>>(
        h8, row2_start, row2_deg, csr2_src, csr_w, bnsc1, bnsh1, hb1);

    // ---- layer 2: hb1 -> hb2[N,128] (bf16) ----
    mfma_feat_kernel<64><<<(NN + 63) / 64, 512, 0, stream>>>(
        hb1, wfrag2, p2b, as2, ad2, h8, esrc, edst, hb2);
    edgew_kernel<<<(NN + 7) / 8, 256, 0, stream>>>(
        csr2_src, row2_start, row2_deg, (const float2*)esrc, (const float2*)edst, csr_w, NN);
    aggregate128_kernel<<<2048, 256, 0, stream>>>(
        h8, row2_start, row2_deg, csr2_src, csr_w, bnsc2, bnsh2, hb2);

    // ---- layer 3: hb2 -> hb3[N,128] (bf16) ----
    mfma_feat_kernel<128><<<(NN + 63) / 64, 512, 0, stream>>>(
        hb2, wfrag3, p3b, as3, ad3, h8, esrc, edst, hb3);
    edgew_kernel<<<(NN + 7) / 8, 256, 0, stream>>>(
        csr2_src, row2_start, row2_deg, (const float2*)esrc, (const float2*)edst, csr_w, NN);
    aggregate128_kernel<<<2048, 256, 0, stream>>>(
        h8, row2_start, row2_deg, csr2_src, csr_w, bnsc3, bnsh3, hb3);

    // ---- pool (two-phase) + head ----
    pool_partial_kernel<<<GG * PSPLIT, 128, 0, stream>>>(hb3, batch, ppart);
    head_kernel<<<GG, 128, 0, stream>>>(ppart, batch, fw, fb, g4, be4, m4, v4,
                                        l1w, l1b, l2w, l2b, (float*)d_out);
}

// Round 9
// 471.260 us; speedup vs baseline: 1.0626x; 1.0626x over previous
//
#include <hip/hip_runtime.h>
#include <hip/hip_bf16.h>
#include <hip/hip_fp16.h>

#define NN   100000
#define EE   1600000
#define ETOT (EE + NN)
#define GG   256
#define BNEPS 1e-5f
#define NBK  391          // buckets of 256 nodes: (NN+255)/256
#define PADTOT (ETOT + NBK * 4096 + 64)
#define PSPLIT 16

typedef float floatx2 __attribute__((ext_vector_type(2)));
typedef short s16x8 __attribute__((ext_vector_type(8)));
typedef float f32x4v __attribute__((ext_vector_type(4)));

__device__ __forceinline__ unsigned short f2bf(float f) {
    unsigned u = __float_as_uint(f);
    unsigned r = u + 0x7FFF + ((u >> 16) & 1);
    return (unsigned short)(r >> 16);
}
__device__ __forceinline__ float bf2f(unsigned short b) {
    return __uint_as_float(((unsigned)b) << 16);
}
// packed 2xfp32 FMA → v_pk_fma_f32
__device__ __forceinline__ floatx2 pkfma(floatx2 a, floatx2 b, floatx2 c) {
    return __builtin_elementwise_fma(a, b, c);
}

// ---------------- CSR build: bucketed partition (single-writer cache lines) --

__global__ __launch_bounds__(256) void bucket_count_kernel(
    const int* __restrict__ ei, int* __restrict__ bucket_cnt)
{
    __shared__ int cnt[NBK];
    for (int i = threadIdx.x; i < NBK; i += 256) cnt[i] = 0;
    __syncthreads();
    int base = blockIdx.x * 8192;
    for (int k = threadIdx.x; k < 8192; k += 256) {
        int e = base + k;
        if (e < ETOT) {
            int dst = (e < EE) ? ei[EE + e] : (e - EE);
            atomicAdd(&cnt[dst >> 8], 1);
        }
    }
    __syncthreads();
    for (int i = threadIdx.x; i < NBK; i += 256)
        if (cnt[i]) atomicAdd(&bucket_cnt[i], cnt[i]);
}

// also plants the -inf esrc sentinel used by pad edges (src = NN)
__global__ __launch_bounds__(512) void bucket_scan_kernel(
    const int* __restrict__ bucket_cnt, int* __restrict__ bucket_base,
    int* __restrict__ gcursor, float* __restrict__ esrcs)
{
    __shared__ int s[512];
    int t = threadIdx.x;
    int v = (t < NBK) ? bucket_cnt[t] : 0;
    s[t] = v;
    __syncthreads();
    int x = v;
    for (int o = 1; o < 512; o <<= 1) {
        int y = (t >= o) ? s[t - o] : 0;
        __syncthreads();
        x += y;
        s[t] = x;
        __syncthreads();
    }
    if (t < NBK) { bucket_base[t] = x - v; gcursor[t] = x - v; }
    if (t == 0) {
        bucket_base[NBK] = ETOT;
        esrcs[2 * NN]     = __int_as_float(0xFF800000);  // -inf
        esrcs[2 * NN + 1] = __int_as_float(0xFF800000);
    }
}

__global__ __launch_bounds__(256) void partition_kernel(
    const int* __restrict__ ei, int* __restrict__ gcursor, int* __restrict__ part)
{
    __shared__ int cnt[NBK];
    __shared__ int basel[NBK];
    for (int i = threadIdx.x; i < NBK; i += 256) cnt[i] = 0;
    __syncthreads();
    int base = blockIdx.x * 4096;
    for (int k = threadIdx.x; k < 4096; k += 256) {
        int e = base + k;
        if (e < ETOT) {
            int dst = (e < EE) ? ei[EE + e] : (e - EE);
            atomicAdd(&cnt[dst >> 8], 1);
        }
    }
    __syncthreads();
    for (int i = threadIdx.x; i < NBK; i += 256) {
        int c = cnt[i];
        basel[i] = c ? atomicAdd(&gcursor[i], c) : 0;
        cnt[i] = 0;   // reuse as intra-block cursor
    }
    __syncthreads();
    for (int k = threadIdx.x; k < 4096; k += 256) {
        int e = base + k;
        if (e < ETOT) {
            int src, dst;
            if (e < EE) { src = ei[e]; dst = ei[EE + e]; }
            else        { src = e - EE; dst = e - EE; }
            int b = dst >> 8;
            int slot = atomicAdd(&cnt[b], 1);
            part[basel[b] + slot] = src | ((dst & 255) << 17);
        }
    }
}

// Padded CSR: per-node segments rounded up to 8 entries (pad-8, R3 win).
// Pad src = NN (sentinel: esrc[NN] = -inf → exp weight 0).
__global__ __launch_bounds__(256) void csr_build_kernel(
    const int* __restrict__ part, const int* __restrict__ bucket_base,
    int* __restrict__ row2_start, int* __restrict__ row2_deg,
    int* __restrict__ csr2_src)
{
    __shared__ int degs[256];
    __shared__ int sc[256];
    __shared__ int cur[256];
    int b = blockIdx.x;
    int t = threadIdx.x;
    int beg = bucket_base[b], end = bucket_base[b + 1];
    int pbase = ((beg + 7) & ~7) + 4096 * b;
    degs[t] = 0;
    __syncthreads();
    for (int j = beg + t; j < end; j += 256)
        atomicAdd(&degs[(part[j] >> 17) & 255], 1);
    __syncthreads();
    int dg = degs[t];
    int pdeg = (dg + 7) & ~7;
    sc[t] = pdeg;
    __syncthreads();
    int x = pdeg;
    for (int o = 1; o < 256; o <<= 1) {
        int y = (t >= o) ? sc[t - o] : 0;
        __syncthreads();
        x += y;
        sc[t] = x;
        __syncthreads();
    }
    int start2 = pbase + (x - pdeg);
    int node = b * 256 + t;
    if (node < NN) { row2_start[node] = start2; row2_deg[node] = dg; }
    cur[t] = start2;
    __syncthreads();
    for (int j = beg + t; j < end; j += 256) {
        int pv = part[j];
        int pos = atomicAdd(&cur[(pv >> 17) & 255], 1);
        csr2_src[pos] = pv & 0x1FFFF;
    }
    for (int k = dg; k < pdeg; ++k) csr2_src[start2 + k] = NN;
}

// ---------------- merged prep: W-fragments (both layers) + fused BN ----------

template<int K>
__device__ __forceinline__ void prep_w_body(
    int unit, const float* __restrict__ W, const float* __restrict__ pw,
    short* __restrict__ wfrag)
{
    constexpr int KS = K / 32;
    int total = 16 * KS * 2 * 64;
    if (unit >= total) return;
    int lane = unit & 63;
    int rest = unit >> 6;
    int hilo = rest & 1;
    int fk = rest >> 1;
    int ks = fk % KS;
    int nt = fk / KS;
    int n = nt * 16 + (lane & 15);
    int k0 = ks * 32 + (lane >> 4) * 8;
    const float* src = (n < 128) ? (W + n) : (pw + (n - 128));
    s16x8 out;
#pragma unroll
    for (int j = 0; j < 8; ++j) {
        float wv = src[(size_t)(k0 + j) * 128];
        unsigned short hi = f2bf(wv);
        if (hilo == 0) {
            out[j] = (short)hi;
        } else {
            float fhi = __uint_as_float(((unsigned)hi) << 16);
            out[j] = (short)f2bf(wv - fhi);
        }
    }
    *(s16x8*)(wfrag + (size_t)unit * 8) = out;
}

__global__ __launch_bounds__(256) void prep_all_kernel(
    const float* __restrict__ w2, const float* __restrict__ p2w, short* __restrict__ wfrag2,
    const float* __restrict__ w3, const float* __restrict__ p3w, short* __restrict__ wfrag3,
    const float* b1, const float* g1, const float* be1, const float* m1, const float* v1,
    const float* b2, const float* g2, const float* be2, const float* m2, const float* v2,
    const float* b3, const float* g3, const float* be3, const float* m3, const float* v3,
    float* sc1, float* sh1, float* sc2, float* sh2, float* sc3, float* sh3)
{
    int b = blockIdx.x;
    int tid = threadIdx.x;
    if (b < 16) {
        prep_w_body<64>(b * 256 + tid, w2, p2w, wfrag2);
    } else if (b < 48) {
        prep_w_body<128>((b - 16) * 256 + tid, w3, p3w, wfrag3);
    } else {
        int t = tid;
        if (t < 128) {
            if (t < 64) {
                float sc = g1[t] * rsqrtf(v1[t] + BNEPS);
                sc1[t] = sc;
                sh1[t] = (b1[t] - m1[t]) * sc + be1[t];
            }
            {
                float sc = g2[t] * rsqrtf(v2[t] + BNEPS);
                sc2[t] = sc;
                sh2[t] = (b2[t] - m2[t]) * sc + be2[t];
            }
            {
                float sc = g3[t] * rsqrtf(v3[t] + BNEPS);
                sc3[t] = sc;
                sh3[t] = (b3[t] - m3[t]) * sc + be3[t];
            }
        }
    }
}

// ---------------- per-layer edge softmax weights (packed 2×bf16) -------------
// R8 win (kept): 2 nodes/wave (32 lanes each) — mean padded degree ~21 left
// 2/3 of a 64-lane wave idle per node.

__global__ __launch_bounds__(256) void edgew_kernel(
    const int* __restrict__ csr2_src, const int* __restrict__ row2_start,
    const int* __restrict__ row2_deg,
    const float2* __restrict__ esrc, const float2* __restrict__ edst,
    unsigned* __restrict__ csr_w, int nN)
{
    int n = blockIdx.x * 8 + (threadIdx.x >> 5);
    int hl = threadIdx.x & 31;
    if (n >= nN) return;
    float2 ed = edst[n];
    int s2 = row2_start[n];
    int dg = row2_deg[n];
    int pc = (dg + 7) & ~7;
    for (int j = hl; j < pc; j += 32) {
        int i = csr2_src[s2 + j];
        float2 es = esrc[i];
        float a0 = es.x + ed.x; a0 = (a0 > 0.f) ? a0 : 0.2f * a0;
        float a1 = es.y + ed.y; a1 = (a1 > 0.f) ? a1 : 0.2f * a1;
        unsigned w = (unsigned)f2bf(__expf(a0)) | ((unsigned)f2bf(__expf(a1)) << 16);
        csr_w[s2 + j] = w;
    }
}

// ---------------- layer-1 feature transform (K=5); h fp8, rout bf16 ----------

__global__ __launch_bounds__(256) void feat1_kernel(
    const float* __restrict__ xin, const float* __restrict__ W,
    const float* __restrict__ pw, const float* __restrict__ pb,
    const float* __restrict__ a_src, const float* __restrict__ a_dst,
    unsigned char* __restrict__ h8, float* __restrict__ esrc, float* __restrict__ edst,
    unsigned short* __restrict__ rout16, int nN)
{
    constexpr int F_IN = 5, F_OUT = 64;
    int t = threadIdx.x;
    int n = blockIdx.x * 4 + t / F_OUT;
    int f = t % F_OUT;
    if (n >= nN) return;
    float acc = 0.f, racc = 0.f;
#pragma unroll
    for (int k = 0; k < F_IN; ++k) {
        float xv = xin[n * F_IN + k];
        acc  += xv * W[k * F_OUT + f];
        racc += xv * pw[k * F_OUT + f];
    }
    float other = __shfl_xor(acc, 1, 64);
    if ((f & 1) == 0) {
        int p = __builtin_amdgcn_cvt_pk_fp8_f32(acc, other, 0, false);
        *(unsigned short*)(h8 + (size_t)n * F_OUT + f) = (unsigned short)(p & 0xFFFF);
    }
    rout16[(size_t)n * F_OUT + f] = f2bf(racc + pb[f]);
    float es = acc * a_src[f];
    float ed = acc * a_dst[f];
#pragma unroll
    for (int off = 16; off > 0; off >>= 1) {
        es += __shfl_xor(es, off, 32);
        ed += __shfl_xor(ed, off, 32);
    }
    if ((t & 31) == 0) {
        int head = (f >> 5) & 1;
        esrc[n * 2 + head] = es;
        edst[n * 2 + head] = ed;
    }
}

// ---------------- MFMA feature transform (layers 2,3; N=256 = W‖pw) ----------
// R7 WIN: column-split dataflow — each wave owns 2 nt-columns, b-frags loaded
// once into registers, rows stream from LDS. Unchanged.

template<int K>
__global__ __launch_bounds__(512, 4) void mfma_feat_kernel(
    const unsigned short* __restrict__ xin16, const short* __restrict__ wfrag,
    const float* __restrict__ pb,
    const float* __restrict__ a_src, const float* __restrict__ a_dst,
    unsigned char* __restrict__ h8, float* __restrict__ esrc, float* __restrict__ edst,
    unsigned short* __restrict__ rout16)
{
    constexpr int KS = K / 32;    // MFMA k-steps
    constexpr int CH = K / 8;     // 8-feature (16 B) chunks per node row
    __shared__ __align__(16) char smem[1024 * CH + 28672];
    s16x8* xs = (s16x8*)smem;                                              // [4][CH][16] tiles
    unsigned short* h8lds = (unsigned short*)(smem + 1024 * CH);           // [64][72]
    unsigned short* rolds = (unsigned short*)(smem + 1024 * CH + 9216);    // [64][136]
    float2* espart = (float2*)(smem + 1024 * CH + 26624);                  // [4][64] {es,ed}

    const int tid = threadIdx.x;
    const int base = blockIdx.x * 64;

    for (int idx = tid; idx < 64 * CH; idx += 512) {
        int node = idx / CH;
        int ch = idx % CH;
        int gn = base + node; if (gn > NN - 1) gn = NN - 1;
        s16x8 v = *(const s16x8*)(xin16 + (size_t)gn * K + ch * 8);
        int tt = node >> 4, mm = node & 15;
        xs[(tt * CH + ch) * 16 + mm] = v;
    }
    __syncthreads();

    const int w = tid >> 6;             // 0..7: column-pair owner
    const int lane = tid & 63;
    const int quad = lane >> 4;
    const int m = lane & 15;
    const int nt0 = 2 * w, nt1 = nt0 + 1;

    // b-fragments for this wave's two output columns: loaded ONCE.
    s16x8 bA[2 * KS], bB[2 * KS];
#pragma unroll
    for (int i = 0; i < 2 * KS; ++i) {
        bA[i] = *(const s16x8*)(wfrag + (size_t)((nt0 * KS * 2 + i) * 64 + lane) * 8);
        bB[i] = *(const s16x8*)(wfrag + (size_t)((nt1 * KS * 2 + i) * 64 + lane) * 8);
    }

    const bool hpart = (w < 4);
    float av0 = 0.f, dv0 = 0.f, av1 = 0.f, dv1 = 0.f, bv0 = 0.f, bv1 = 0.f;
    if (hpart) {
        av0 = a_src[nt0 * 16 + m]; dv0 = a_dst[nt0 * 16 + m];
        av1 = a_src[nt1 * 16 + m]; dv1 = a_dst[nt1 * 16 + m];
    } else {
        bv0 = pb[(nt0 - 8) * 16 + m]; bv1 = pb[(nt1 - 8) * 16 + m];
    }

#pragma unroll
    for (int rt = 0; rt < 4; ++rt) {
        s16x8 a[KS];
#pragma unroll
        for (int ks = 0; ks < KS; ++ks)
            a[ks] = xs[(rt * CH + ks * 4 + quad) * 16 + m];
        f32x4v cA = {0.f, 0.f, 0.f, 0.f};
        f32x4v cB = {0.f, 0.f, 0.f, 0.f};
#pragma unroll
        for (int ks = 0; ks < KS; ++ks) {
            cA = __builtin_amdgcn_mfma_f32_16x16x32_bf16(a[ks], bA[2 * ks + 0], cA, 0, 0, 0);
            cA = __builtin_amdgcn_mfma_f32_16x16x32_bf16(a[ks], bA[2 * ks + 1], cA, 0, 0, 0);
            cB = __builtin_amdgcn_mfma_f32_16x16x32_bf16(a[ks], bB[2 * ks + 0], cB, 0, 0, 0);
            cB = __builtin_amdgcn_mfma_f32_16x16x32_bf16(a[ks], bB[2 * ks + 1], cB, 0, 0, 0);
        }
        int row0 = rt * 16 + quad * 4;
        if (hpart) {
#pragma unroll
            for (int r = 0; r < 4; ++r) {
                float v0 = cA[r], v1 = cB[r];
                float es = v0 * av0 + v1 * av1;
                float ed = v0 * dv0 + v1 * dv1;
#pragma unroll
                for (int off = 8; off > 0; off >>= 1) {
                    es += __shfl_xor(es, off, 16);
                    ed += __shfl_xor(ed, off, 16);
                }
                if (m == 0) espart[w * 64 + row0 + r] = make_float2(es, ed);
                float p0 = __shfl_xor(v0, 1, 16);
                float p1 = __shfl_xor(v1, 1, 16);
                if ((m & 1) == 0) {
                    int pk0 = __builtin_amdgcn_cvt_pk_fp8_f32(v0, p0, 0, false);
                    int pk1 = __builtin_amdgcn_cvt_pk_fp8_f32(v1, p1, 0, false);
                    h8lds[(row0 + r) * 72 + nt0 * 8 + (m >> 1)] = (unsigned short)(pk0 & 0xFFFF);
                    h8lds[(row0 + r) * 72 + nt1 * 8 + (m >> 1)] = (unsigned short)(pk1 & 0xFFFF);
                }
            }
        } else {
#pragma unroll
            for (int r = 0; r < 4; ++r) {
                rolds[(row0 + r) * 136 + (nt0 - 8) * 16 + m] = f2bf(cA[r] + bv0);
                rolds[(row0 + r) * 136 + (nt1 - 8) * 16 + m] = f2bf(cB[r] + bv1);
            }
        }
    }

    __syncthreads();

    // es/ed cross-wave reduce: head0 = waves 0,1 (cols 0..63); head1 = waves 2,3.
    if (tid < 64) {
        int node = base + tid;
        if (node < NN) {
            float2 e0 = espart[0 * 64 + tid];
            float2 e1 = espart[1 * 64 + tid];
            float2 e2 = espart[2 * 64 + tid];
            float2 e3 = espart[3 * 64 + tid];
            ((float2*)esrc)[node] = make_float2(e0.x + e1.x, e2.x + e3.x);
            ((float2*)edst)[node] = make_float2(e0.y + e1.y, e2.y + e3.y);
        }
    }
    for (int i = tid; i < 64 * 8; i += 512) {
        int row = i >> 3, ch = i & 7;
        int node = base + row;
        if (node < NN) {
            int4 v = *(const int4*)((char*)h8lds + row * 144 + ch * 16);
            *(int4*)(h8 + (size_t)node * 128 + ch * 16) = v;
        }
    }
    for (int i = tid; i < 64 * 16; i += 512) {
        int row = i >> 4, ch = i & 15;
        int node = base + row;
        if (node < NN) {
            int4 v = *(const int4*)((char*)rolds + row * 272 + ch * 16);
            *(int4*)((char*)rout16 + (size_t)node * 256 + ch * 16) = v;
        }
    }
}

// ---------------- fused aggregate, F=128 (two nodes/wave; int4 CSR loads) ----
// R9: revert R8's persistent grid (regressed: static assignment loses the
// dispatcher's free load-balancing). Back to R7 dispatch form + split
// accumulator chains (a/b) to halve the per-iteration pkfma critical path.

__global__ __launch_bounds__(256) void aggregate128_kernel(
    const unsigned char* __restrict__ h8,
    const int* __restrict__ row2_start, const int* __restrict__ row2_deg,
    const int* __restrict__ csr2_src, const unsigned* __restrict__ csr_w,
    const float* __restrict__ bnsc, const float* __restrict__ bnsh,
    unsigned short* __restrict__ io16)
{
    int w = threadIdx.x >> 6;
    int lane = threadIdx.x & 63;
    int half = lane >> 5;
    int fl = lane & 31;               // dword within the 128 B row (4 features)
    unsigned shl = (fl >= 16) ? 0u : 16u;   // head1 keeps hi bf16, head0 shifts up
    int n = blockIdx.x * 8 + w * 2 + half;
    int s2 = row2_start[n];
    int dg = row2_deg[n];
    int pc = (dg + 7) & ~7;
    const int4* sp = (const int4*)(csr2_src + s2);
    const uint4* wp = (const uint4*)(csr_w + s2);
    float sa = 0.f, sb = 0.f;
    floatx2 acc01a = {0.f, 0.f}, acc23a = {0.f, 0.f};
    floatx2 acc01b = {0.f, 0.f}, acc23b = {0.f, 0.f};
    for (int j = 0; j < pc; j += 8) {
        int4 ia = sp[(j >> 2) + 0];
        int4 ib = sp[(j >> 2) + 1];
        uint4 wa = wp[(j >> 2) + 0];
        uint4 wb = wp[(j >> 2) + 1];
        unsigned d0 = *(const unsigned*)(h8 + (size_t)ia.x * 128 + fl * 4);
        unsigned d1 = *(const unsigned*)(h8 + (size_t)ia.y * 128 + fl * 4);
        unsigned d2 = *(const unsigned*)(h8 + (size_t)ia.z * 128 + fl * 4);
        unsigned d3 = *(const unsigned*)(h8 + (size_t)ia.w * 128 + fl * 4);
        unsigned d4 = *(const unsigned*)(h8 + (size_t)ib.x * 128 + fl * 4);
        unsigned d5 = *(const unsigned*)(h8 + (size_t)ib.y * 128 + fl * 4);
        unsigned d6 = *(const unsigned*)(h8 + (size_t)ib.z * 128 + fl * 4);
        unsigned d7 = *(const unsigned*)(h8 + (size_t)ib.w * 128 + fl * 4);
        float g0 = __uint_as_float((wa.x << shl) & 0xFFFF0000u);
        float g1 = __uint_as_float((wa.y << shl) & 0xFFFF0000u);
        float g2 = __uint_as_float((wa.z << shl) & 0xFFFF0000u);
        float g3 = __uint_as_float((wa.w << shl) & 0xFFFF0000u);
        float g4 = __uint_as_float((wb.x << shl) & 0xFFFF0000u);
        float g5 = __uint_as_float((wb.y << shl) & 0xFFFF0000u);
        float g6 = __uint_as_float((wb.z << shl) & 0xFFFF0000u);
        float g7 = __uint_as_float((wb.w << shl) & 0xFFFF0000u);
        floatx2 gv0 = {g0, g0};
        floatx2 gv1 = {g1, g1};
        floatx2 gv2 = {g2, g2};
        floatx2 gv3 = {g3, g3};
        floatx2 gv4 = {g4, g4};
        floatx2 gv5 = {g5, g5};
        floatx2 gv6 = {g6, g6};
        floatx2 gv7 = {g7, g7};
        acc01a = pkfma(gv0, __builtin_amdgcn_cvt_pk_f32_fp8((int)d0, false), acc01a);
        acc23a = pkfma(gv0, __builtin_amdgcn_cvt_pk_f32_fp8((int)d0, true),  acc23a);
        acc01a = pkfma(gv1, __builtin_amdgcn_cvt_pk_f32_fp8((int)d1, false), acc01a);
        acc23a = pkfma(gv1, __builtin_amdgcn_cvt_pk_f32_fp8((int)d1, true),  acc23a);
        acc01a = pkfma(gv2, __builtin_amdgcn_cvt_pk_f32_fp8((int)d2, false), acc01a);
        acc23a = pkfma(gv2, __builtin_amdgcn_cvt_pk_f32_fp8((int)d2, true),  acc23a);
        acc01a = pkfma(gv3, __builtin_amdgcn_cvt_pk_f32_fp8((int)d3, false), acc01a);
        acc23a = pkfma(gv3, __builtin_amdgcn_cvt_pk_f32_fp8((int)d3, true),  acc23a);
        acc01b = pkfma(gv4, __builtin_amdgcn_cvt_pk_f32_fp8((int)d4, false), acc01b);
        acc23b = pkfma(gv4, __builtin_amdgcn_cvt_pk_f32_fp8((int)d4, true),  acc23b);
        acc01b = pkfma(gv5, __builtin_amdgcn_cvt_pk_f32_fp8((int)d5, false), acc01b);
        acc23b = pkfma(gv5, __builtin_amdgcn_cvt_pk_f32_fp8((int)d5, true),  acc23b);
        acc01b = pkfma(gv6, __builtin_amdgcn_cvt_pk_f32_fp8((int)d6, false), acc01b);
        acc23b = pkfma(gv6, __builtin_amdgcn_cvt_pk_f32_fp8((int)d6, true),  acc23b);
        acc01b = pkfma(gv7, __builtin_amdgcn_cvt_pk_f32_fp8((int)d7, false), acc01b);
        acc23b = pkfma(gv7, __builtin_amdgcn_cvt_pk_f32_fp8((int)d7, true),  acc23b);
        sa += ((g0 + g1) + (g2 + g3));
        sb += ((g4 + g5) + (g6 + g7));
    }
    floatx2 acc01 = acc01a + acc01b;
    floatx2 acc23 = acc23a + acc23b;
    float s = sa + sb;
    float inv = 1.f / (s + 1e-16f);
    int f0 = fl * 4;
    float4 sc = *(const float4*)(bnsc + f0);
    float4 sh = *(const float4*)(bnsh + f0);
    float o0 = fmaf(acc01.x * inv, sc.x, sh.x);
    float o1 = fmaf(acc01.y * inv, sc.y, sh.y);
    float o2 = fmaf(acc23.x * inv, sc.z, sh.z);
    float o3 = fmaf(acc23.y * inv, sc.w, sh.w);
    uint2* iop = (uint2*)(io16 + (size_t)n * 128 + f0);
    uint2 pu = *iop;
    float r0 = fmaxf(o0, 0.f) + __uint_as_float((pu.x & 0xFFFFu) << 16);
    float r1 = fmaxf(o1, 0.f) + __uint_as_float(pu.x & 0xFFFF0000u);
    float r2 = fmaxf(o2, 0.f) + __uint_as_float((pu.y & 0xFFFFu) << 16);
    float r3 = fmaxf(o3, 0.f) + __uint_as_float(pu.y & 0xFFFF0000u);
    uint2 ov;
    ov.x = (unsigned)f2bf(r0) | ((unsigned)f2bf(r1) << 16);
    ov.y = (unsigned)f2bf(r2) | ((unsigned)f2bf(r3) << 16);
    *iop = ov;
}

// ---------------- fused aggregate, F=64 (two nodes/wave, pk_fma) -------------

__global__ __launch_bounds__(256) void aggregate64_kernel(
    const unsigned char* __restrict__ h8,
    const int* __restrict__ row2_start, const int* __restrict__ row2_deg,
    const int* __restrict__ csr2_src, const unsigned* __restrict__ csr_w,
    const float* __restrict__ bnsc, const float* __restrict__ bnsh,
    unsigned short* __restrict__ io16)
{
    int w = threadIdx.x >> 6;
    int lane = threadIdx.x & 63;
    int half = lane >> 5;
    int hl = lane & 31;
    int q  = hl >> 4;                 // edge selector within pair
    int fl = hl & 15;                 // feature dword (features 4fl..4fl+3)
    unsigned shl = (fl >= 8) ? 0u : 16u;
    int n = blockIdx.x * 8 + w * 2 + half;
    int s2 = row2_start[n];
    int dg = row2_deg[n];
    int pc = (dg + 7) & ~7;
    const int4* sp = (const int4*)(csr2_src + s2);
    const uint4* wp = (const uint4*)(csr_w + s2);
    float s = 0.f;
    floatx2 acc01 = {0.f, 0.f}, acc23 = {0.f, 0.f};
    for (int j = 0; j < pc; j += 8) {
        int4 ia = sp[(j >> 2) + 0];
        int4 ib = sp[(j >> 2) + 1];
        uint4 wa = wp[(j >> 2) + 0];
        uint4 wb = wp[(j >> 2) + 1];
        int i0 = q ? ia.y : ia.x;
        int i1 = q ? ia.w : ia.z;
        int i2 = q ? ib.y : ib.x;
        int i3 = q ? ib.w : ib.z;
        unsigned w0 = q ? wa.y : wa.x;
        unsigned w1 = q ? wa.w : wa.z;
        unsigned w2 = q ? wb.y : wb.x;
        unsigned w3 = q ? wb.w : wb.z;
        unsigned d0 = *(const unsigned*)(h8 + (size_t)i0 * 64 + fl * 4);
        unsigned d1 = *(const unsigned*)(h8 + (size_t)i1 * 64 + fl * 4);
        unsigned d2 = *(const unsigned*)(h8 + (size_t)i2 * 64 + fl * 4);
        unsigned d3 = *(const unsigned*)(h8 + (size_t)i3 * 64 + fl * 4);
        float g0 = __uint_as_float((w0 << shl) & 0xFFFF0000u);
        float g1 = __uint_as_float((w1 << shl) & 0xFFFF0000u);
        float g2 = __uint_as_float((w2 << shl) & 0xFFFF0000u);
        float g3 = __uint_as_float((w3 << shl) & 0xFFFF0000u);
        floatx2 gv0 = {g0, g0};
        floatx2 gv1 = {g1, g1};
        floatx2 gv2 = {g2, g2};
        floatx2 gv3 = {g3, g3};
        acc01 = pkfma(gv0, __builtin_amdgcn_cvt_pk_f32_fp8((int)d0, false), acc01);
        acc23 = pkfma(gv0, __builtin_amdgcn_cvt_pk_f32_fp8((int)d0, true),  acc23);
        acc01 = pkfma(gv1, __builtin_amdgcn_cvt_pk_f32_fp8((int)d1, false), acc01);
        acc23 = pkfma(gv1, __builtin_amdgcn_cvt_pk_f32_fp8((int)d1, true),  acc23);
        acc01 = pkfma(gv2, __builtin_amdgcn_cvt_pk_f32_fp8((int)d2, false), acc01);
        acc23 = pkfma(gv2, __builtin_amdgcn_cvt_pk_f32_fp8((int)d2, true),  acc23);
        acc01 = pkfma(gv3, __builtin_amdgcn_cvt_pk_f32_fp8((int)d3, false), acc01);
        acc23 = pkfma(gv3, __builtin_amdgcn_cvt_pk_f32_fp8((int)d3, true),  acc23);
        s += ((g0 + g1) + (g2 + g3));
    }
    // combine the two quarters within each half (xor 16 stays inside the half)
    acc01.x += __shfl_xor(acc01.x, 16);
    acc01.y += __shfl_xor(acc01.y, 16);
    acc23.x += __shfl_xor(acc23.x, 16);
    acc23.y += __shfl_xor(acc23.y, 16);
    s += __shfl_xor(s, 16);
    if (hl < 16) {
        float inv = 1.f / (s + 1e-16f);
        int f0 = fl * 4;
        float4 sc = *(const float4*)(bnsc + f0);
        float4 sh = *(const float4*)(bnsh + f0);
        float o0 = fmaf(acc01.x * inv, sc.x, sh.x);
        float o1 = fmaf(acc01.y * inv, sc.y, sh.y);
        float o2 = fmaf(acc23.x * inv, sc.z, sh.z);
        float o3 = fmaf(acc23.y * inv, sc.w, sh.w);
        uint2* iop = (uint2*)(io16 + (size_t)n * 64 + f0);
        uint2 pu = *iop;
        float r0 = fmaxf(o0, 0.f) + __uint_as_float((pu.x & 0xFFFFu) << 16);
        float r1 = fmaxf(o1, 0.f) + __uint_as_float(pu.x & 0xFFFF0000u);
        float r2 = fmaxf(o2, 0.f) + __uint_as_float((pu.y & 0xFFFFu) << 16);
        float r3 = fmaxf(o3, 0.f) + __uint_as_float(pu.y & 0xFFFF0000u);
        uint2 ov;
        ov.x = (unsigned)f2bf(r0) | ((unsigned)f2bf(r1) << 16);
        ov.y = (unsigned)f2bf(r2) | ((unsigned)f2bf(r3) << 16);
        *iop = ov;
    }
}

// ---------------- pooling, two-phase (bf16 input) ----------------

__global__ __launch_bounds__(128) void pool_partial_kernel(
    const unsigned short* __restrict__ hf16, const int* __restrict__ batch,
    float* __restrict__ ppart)
{
    int g = blockIdx.x / PSPLIT;
    int p = blockIdx.x % PSPLIT;
    int f = threadIdx.x;
    int lo = 0, hi = NN;
    while (lo < hi) { int mid = (lo + hi) >> 1; if (batch[mid] < g) lo = mid + 1; else hi = mid; }
    int start = lo;
    hi = NN;
    while (lo < hi) { int mid = (lo + hi) >> 1; if (batch[mid] < g + 1) lo = mid + 1; else hi = mid; }
    int end = lo;
    int len = end - start;
    int chunk = (len + PSPLIT - 1) / PSPLIT;
    int i0 = start + p * chunk;
    int i1 = i0 + chunk; if (i1 > end) i1 = end;
    float acc = 0.f;
    for (int i = i0; i < i1; ++i) acc += bf2f(hf16[(size_t)i * 128 + f]);
    ppart[((size_t)g * PSPLIT + p) * 128 + f] = acc;
}

// ---------------- MLP head (folds partial-sum reduce + mean) -----------------

__global__ __launch_bounds__(128) void head_kernel(
    const float* __restrict__ ppart, const int* __restrict__ batch,
    const float* __restrict__ fw, const float* __restrict__ fb,
    const float* __restrict__ g4, const float* __restrict__ be4,
    const float* __restrict__ m4, const float* __restrict__ v4,
    const float* __restrict__ l1w, const float* __restrict__ l1b,
    const float* __restrict__ l2w, const float* __restrict__ l2b,
    float* __restrict__ out)
{
    __shared__ float p[128];
    __shared__ float z1[32];
    __shared__ float z2[32];
    int g = blockIdx.x, t = threadIdx.x;
    int lo = 0, hi = NN;
    while (lo < hi) { int mid = (lo + hi) >> 1; if (batch[mid] < g) lo = mid + 1; else hi = mid; }
    int start = lo;
    hi = NN;
    while (lo < hi) { int mid = (lo + hi) >> 1; if (batch[mid] < g + 1) lo = mid + 1; else hi = mid; }
    float cnt = (float)(lo - start);
    float acc = 0.f;
#pragma unroll
    for (int q = 0; q < PSPLIT; ++q)
        acc += ppart[((size_t)g * PSPLIT + q) * 128 + t];
    p[t] = acc / fmaxf(cnt, 1.0f);
    __syncthreads();
    if (t < 32) {
        float a = fb[t];
        for (int k = 0; k < 128; ++k) a += p[k] * fw[k * 32 + t];
        float val = g4[t] * (a - m4[t]) * rsqrtf(v4[t] + BNEPS) + be4[t];
        z1[t] = fmaxf(val, 0.f);
    }
    __syncthreads();
    if (t < 32) {
        float a = l1b[t];
        for (int k = 0; k < 32; ++k) a += z1[k] * l1w[k * 32 + t];
        z2[t] = fmaxf(a, 0.f);
    }
    __syncthreads();
    if (t < 10) {
        float a = l2b[t];
        for (int k = 0; k < 32; ++k) a += z2[k] * l2w[k * 10 + t];
        out[g * 10 + t] = a;
    }
}

// ---------------- launch ----------------

extern "C" void kernel_launch(void* const* d_in, const int* in_sizes, int n_in,
                              void* d_out, int out_size, void* d_ws, size_t ws_size,
                              hipStream_t stream) {
    const float* x     = (const float*)d_in[0];
    const int*   ei    = (const int*)d_in[1];
    const int*   batch = (const int*)d_in[2];
    const float* w1  = (const float*)d_in[3];
    const float* as1 = (const float*)d_in[4];
    const float* ad1 = (const float*)d_in[5];
    const float* b1  = (const float*)d_in[6];
    const float* g1  = (const float*)d_in[7];
    const float* be1 = (const float*)d_in[8];
    const float* m1  = (const float*)d_in[9];
    const float* v1  = (const float*)d_in[10];
    const float* p1w = (const float*)d_in[11];
    const float* p1b = (const float*)d_in[12];
    const float* w2  = (const float*)d_in[13];
    const float* as2 = (const float*)d_in[14];
    const float* ad2 = (const float*)d_in[15];
    const float* b2  = (const float*)d_in[16];
    const float* g2  = (const float*)d_in[17];
    const float* be2 = (const float*)d_in[18];
    const float* m2  = (const float*)d_in[19];
    const float* v2  = (const float*)d_in[20];
    const float* p2w = (const float*)d_in[21];
    const float* p2b = (const float*)d_in[22];
    const float* w3  = (const float*)d_in[23];
    const float* as3 = (const float*)d_in[24];
    const float* ad3 = (const float*)d_in[25];
    const float* b3  = (const float*)d_in[26];
    const float* g3  = (const float*)d_in[27];
    const float* be3 = (const float*)d_in[28];
    const float* m3  = (const float*)d_in[29];
    const float* v3  = (const float*)d_in[30];
    const float* p3w = (const float*)d_in[31];
    const float* p3b = (const float*)d_in[32];
    const float* fw  = (const float*)d_in[33];
    const float* fb  = (const float*)d_in[34];
    const float* g4  = (const float*)d_in[35];
    const float* be4 = (const float*)d_in[36];
    const float* m4  = (const float*)d_in[37];
    const float* v4  = (const float*)d_in[38];
    const float* l1w = (const float*)d_in[39];
    const float* l1b = (const float*)d_in[40];
    const float* l2w = (const float*)d_in[41];
    const float* l2b = (const float*)d_in[42];

    char* ws = (char*)d_ws;
    size_t off = 0;
    auto alloc = [&](size_t bytes) -> char* {
        char* p = ws + off;
        off += (bytes + 255) & ~(size_t)255;
        return p;
    };
    int*    bucket_cnt  = (int*)alloc((NBK) * sizeof(int));
    int*    bucket_base = (int*)alloc((NBK + 1) * sizeof(int));
    int*    gcursor     = (int*)alloc((NBK) * sizeof(int));
    int*    part        = (int*)alloc((size_t)ETOT * sizeof(int));
    int*    row2_start  = (int*)alloc(NN * sizeof(int));
    int*    row2_deg    = (int*)alloc(NN * sizeof(int));
    int*    csr2_src    = (int*)alloc((size_t)PADTOT * sizeof(int));
    unsigned* csr_w     = (unsigned*)alloc((size_t)PADTOT * sizeof(unsigned));
    unsigned char*  h8  = (unsigned char*)alloc((size_t)(NN + 1) * 128);
    unsigned short* hb1 = (unsigned short*)alloc((size_t)NN * 64 * sizeof(short));
    unsigned short* hb2 = (unsigned short*)alloc((size_t)NN * 128 * sizeof(short));
    unsigned short* hb3 = (unsigned short*)alloc((size_t)NN * 128 * sizeof(short));
    float*  esrc        = (float*)alloc((size_t)(NN + 1) * 2 * sizeof(float));
    float*  edst        = (float*)alloc((size_t)NN * 2 * sizeof(float));
    float*  ppart       = (float*)alloc((size_t)GG * PSPLIT * 128 * sizeof(float));
    short*  wfrag2      = (short*)alloc((size_t)16 * 2 * 2 * 64 * 8 * sizeof(short));
    short*  wfrag3      = (short*)alloc((size_t)16 * 4 * 2 * 64 * 8 * sizeof(short));
    float*  bnsc1       = (float*)alloc(64 * sizeof(float));
    float*  bnsh1       = (float*)alloc(64 * sizeof(float));
    float*  bnsc2       = (float*)alloc(128 * sizeof(float));
    float*  bnsh2       = (float*)alloc(128 * sizeof(float));
    float*  bnsc3       = (float*)alloc(128 * sizeof(float));
    float*  bnsh3       = (float*)alloc(128 * sizeof(float));

    // ---- merged prep (W fragments + fused BN) ----
    prep_all_kernel<<<49, 256, 0, stream>>>(
        w2, p2w, wfrag2, w3, p3w, wfrag3,
        b1, g1, be1, m1, v1, b2, g2, be2, m2, v2, b3, g3, be3, m3, v3,
        bnsc1, bnsh1, bnsc2, bnsh2, bnsc3, bnsh3);

    // ---- CSR build (bucketed partition, padded-8 layout, NN sentinel) ----
    hipMemsetAsync(bucket_cnt, 0, NBK * sizeof(int), stream);
    bucket_count_kernel<<<(ETOT + 8191) / 8192, 256, 0, stream>>>(ei, bucket_cnt);
    bucket_scan_kernel<<<1, 512, 0, stream>>>(bucket_cnt, bucket_base, gcursor, esrc);
    partition_kernel<<<(ETOT + 4095) / 4096, 256, 0, stream>>>(ei, gcursor, part);
    csr_build_kernel<<<NBK, 256, 0, stream>>>(part, bucket_base, row2_start, row2_deg, csr2_src);

    // ---- layer 1: x[N,5] -> hb1[N,64] (bf16) ----
    feat1_kernel<<<(NN + 3) / 4, 256, 0, stream>>>(
        x, w1, p1w, p1b, as1, ad1, h8, esrc, edst, hb1, NN);
    edgew_kernel<<<(NN + 7) / 8, 256, 0, stream>>>(
        csr2_src, row2_start, row2_deg, (const float2*)esrc, (const float2*)edst, csr_w, NN);
    aggregate64_kernel<<<NN / 8, 256, 0, stream>>>(
        h8, row2_start, row2_deg, csr2_src, csr_w, bnsc1, bnsh1, hb1);

    // ---- layer 2: hb1 -> hb2[N,128] (bf16) ----
    mfma_feat_kernel<64><<<(NN + 63) / 64, 512, 0, stream>>>(
        hb1, wfrag2, p2b, as2, ad2, h8, esrc, edst, hb2);
    edgew_kernel<<<(NN + 7) / 8, 256, 0, stream>>>(
        csr2_src, row2_start, row2_deg, (const float2*)esrc, (const float2*)edst, csr_w, NN);
    aggregate128_kernel<<<NN / 8, 256, 0, stream>>>(
        h8, row2_start, row2_deg, csr2_src, csr_w, bnsc2, bnsh2, hb2);

    // ---- layer 3: hb2 -> hb3[N,128] (bf16) ----
    mfma_feat_kernel<128><<<(NN + 63) / 64, 512, 0, stream>>>(
        hb2, wfrag3, p3b, as3, ad3, h8, esrc, edst, hb3);
    edgew_kernel<<<(NN + 7) / 8, 256, 0, stream>>>(
        csr2_src, row2_start, row2_deg, (const float2*)esrc, (const float2*)edst, csr_w, NN);
    aggregate128_kernel<<<NN / 8, 256, 0, stream>>>(
        h8, row2_start, row2_deg, csr2_src, csr_w, bnsc3, bnsh3, hb3);

    // ---- pool (two-phase) + head ----
    pool_partial_kernel<<<GG * PSPLIT, 128, 0, stream>>>(hb3, batch, ppart);
    head_kernel<<<GG, 128, 0, stream>>>(ppart, batch, fw, fb, g4, be4, m4, v4,
                                        l1w, l1b, l2w, l2b, (float*)d_out);
}

// Round 10
// 433.482 us; speedup vs baseline: 1.1552x; 1.0871x over previous
//
#include <hip/hip_runtime.h>
#include <hip/hip_bf16.h>
#include <hip/hip_fp16.h>

#define NN   100000
#define EE   1600000
#define ETOT (EE + NN)
#define GG   256
#define BNEPS 1e-5f
#define NBK  391          // buckets of 256 nodes: (NN+255)/256
#define PADTOT (ETOT + NBK * 4096 + 64)
#define PSPLIT 16

typedef float floatx2 __attribute__((ext_vector_type(2)));
typedef short s16x8 __attribute__((ext_vector_type(8)));
typedef float f32x4v __attribute__((ext_vector_type(4)));

__device__ __forceinline__ unsigned short f2bf(float f) {
    unsigned u = __float_as_uint(f);
    unsigned r = u + 0x7FFF + ((u >> 16) & 1);
    return (unsigned short)(r >> 16);
}
__device__ __forceinline__ float bf2f(unsigned short b) {
    return __uint_as_float(((unsigned)b) << 16);
}
// packed 2xfp32 FMA → v_pk_fma_f32
__device__ __forceinline__ floatx2 pkfma(floatx2 a, floatx2 b, floatx2 c) {
    return __builtin_elementwise_fma(a, b, c);
}

// ---------------- CSR build: bucketed partition (single-writer cache lines) --

__global__ __launch_bounds__(256) void bucket_count_kernel(
    const int* __restrict__ ei, int* __restrict__ bucket_cnt)
{
    __shared__ int cnt[NBK];
    for (int i = threadIdx.x; i < NBK; i += 256) cnt[i] = 0;
    __syncthreads();
    int base = blockIdx.x * 8192;
    for (int k = threadIdx.x; k < 8192; k += 256) {
        int e = base + k;
        if (e < ETOT) {
            int dst = (e < EE) ? ei[EE + e] : (e - EE);
            atomicAdd(&cnt[dst >> 8], 1);
        }
    }
    __syncthreads();
    for (int i = threadIdx.x; i < NBK; i += 256)
        if (cnt[i]) atomicAdd(&bucket_cnt[i], cnt[i]);
}

// also plants the -inf esrc sentinel used by pad edges (src = NN)
__global__ __launch_bounds__(512) void bucket_scan_kernel(
    const int* __restrict__ bucket_cnt, int* __restrict__ bucket_base,
    int* __restrict__ gcursor, float* __restrict__ esrcs)
{
    __shared__ int s[512];
    int t = threadIdx.x;
    int v = (t < NBK) ? bucket_cnt[t] : 0;
    s[t] = v;
    __syncthreads();
    int x = v;
    for (int o = 1; o < 512; o <<= 1) {
        int y = (t >= o) ? s[t - o] : 0;
        __syncthreads();
        x += y;
        s[t] = x;
        __syncthreads();
    }
    if (t < NBK) { bucket_base[t] = x - v; gcursor[t] = x - v; }
    if (t == 0) {
        bucket_base[NBK] = ETOT;
        esrcs[2 * NN]     = __int_as_float(0xFF800000);  // -inf
        esrcs[2 * NN + 1] = __int_as_float(0xFF800000);
    }
}

__global__ __launch_bounds__(256) void partition_kernel(
    const int* __restrict__ ei, int* __restrict__ gcursor, int* __restrict__ part)
{
    __shared__ int cnt[NBK];
    __shared__ int basel[NBK];
    for (int i = threadIdx.x; i < NBK; i += 256) cnt[i] = 0;
    __syncthreads();
    int base = blockIdx.x * 4096;
    for (int k = threadIdx.x; k < 4096; k += 256) {
        int e = base + k;
        if (e < ETOT) {
            int dst = (e < EE) ? ei[EE + e] : (e - EE);
            atomicAdd(&cnt[dst >> 8], 1);
        }
    }
    __syncthreads();
    for (int i = threadIdx.x; i < NBK; i += 256) {
        int c = cnt[i];
        basel[i] = c ? atomicAdd(&gcursor[i], c) : 0;
        cnt[i] = 0;   // reuse as intra-block cursor
    }
    __syncthreads();
    for (int k = threadIdx.x; k < 4096; k += 256) {
        int e = base + k;
        if (e < ETOT) {
            int src, dst;
            if (e < EE) { src = ei[e]; dst = ei[EE + e]; }
            else        { src = e - EE; dst = e - EE; }
            int b = dst >> 8;
            int slot = atomicAdd(&cnt[b], 1);
            part[basel[b] + slot] = src | ((dst & 255) << 17);
        }
    }
}

// Padded CSR: per-node segments rounded up to 8 entries (pad-8, R3 win).
// Pad src = NN (sentinel: esrc[NN] = -inf → exp weight 0).
__global__ __launch_bounds__(256) void csr_build_kernel(
    const int* __restrict__ part, const int* __restrict__ bucket_base,
    int* __restrict__ row2_start, int* __restrict__ row2_deg,
    int* __restrict__ csr2_src)
{
    __shared__ int degs[256];
    __shared__ int sc[256];
    __shared__ int cur[256];
    int b = blockIdx.x;
    int t = threadIdx.x;
    int beg = bucket_base[b], end = bucket_base[b + 1];
    int pbase = ((beg + 7) & ~7) + 4096 * b;
    degs[t] = 0;
    __syncthreads();
    for (int j = beg + t; j < end; j += 256)
        atomicAdd(&degs[(part[j] >> 17) & 255], 1);
    __syncthreads();
    int dg = degs[t];
    int pdeg = (dg + 7) & ~7;
    sc[t] = pdeg;
    __syncthreads();
    int x = pdeg;
    for (int o = 1; o < 256; o <<= 1) {
        int y = (t >= o) ? sc[t - o] : 0;
        __syncthreads();
        x += y;
        sc[t] = x;
        __syncthreads();
    }
    int start2 = pbase + (x - pdeg);
    int node = b * 256 + t;
    if (node < NN) { row2_start[node] = start2; row2_deg[node] = dg; }
    cur[t] = start2;
    __syncthreads();
    for (int j = beg + t; j < end; j += 256) {
        int pv = part[j];
        int pos = atomicAdd(&cur[(pv >> 17) & 255], 1);
        csr2_src[pos] = pv & 0x1FFFF;
    }
    for (int k = dg; k < pdeg; ++k) csr2_src[start2 + k] = NN;
}

// ---------------- merged prep: W-fragments (both layers) + fused BN ----------

template<int K>
__device__ __forceinline__ void prep_w_body(
    int unit, const float* __restrict__ W, const float* __restrict__ pw,
    short* __restrict__ wfrag)
{
    constexpr int KS = K / 32;
    int total = 16 * KS * 2 * 64;
    if (unit >= total) return;
    int lane = unit & 63;
    int rest = unit >> 6;
    int hilo = rest & 1;
    int fk = rest >> 1;
    int ks = fk % KS;
    int nt = fk / KS;
    int n = nt * 16 + (lane & 15);
    int k0 = ks * 32 + (lane >> 4) * 8;
    const float* src = (n < 128) ? (W + n) : (pw + (n - 128));
    s16x8 out;
#pragma unroll
    for (int j = 0; j < 8; ++j) {
        float wv = src[(size_t)(k0 + j) * 128];
        unsigned short hi = f2bf(wv);
        if (hilo == 0) {
            out[j] = (short)hi;
        } else {
            float fhi = __uint_as_float(((unsigned)hi) << 16);
            out[j] = (short)f2bf(wv - fhi);
        }
    }
    *(s16x8*)(wfrag + (size_t)unit * 8) = out;
}

__global__ __launch_bounds__(256) void prep_all_kernel(
    const float* __restrict__ w2, const float* __restrict__ p2w, short* __restrict__ wfrag2,
    const float* __restrict__ w3, const float* __restrict__ p3w, short* __restrict__ wfrag3,
    const float* b1, const float* g1, const float* be1, const float* m1, const float* v1,
    const float* b2, const float* g2, const float* be2, const float* m2, const float* v2,
    const float* b3, const float* g3, const float* be3, const float* m3, const float* v3,
    float* sc1, float* sh1, float* sc2, float* sh2, float* sc3, float* sh3)
{
    int b = blockIdx.x;
    int tid = threadIdx.x;
    if (b < 16) {
        prep_w_body<64>(b * 256 + tid, w2, p2w, wfrag2);
    } else if (b < 48) {
        prep_w_body<128>((b - 16) * 256 + tid, w3, p3w, wfrag3);
    } else {
        int t = tid;
        if (t < 128) {
            if (t < 64) {
                float sc = g1[t] * rsqrtf(v1[t] + BNEPS);
                sc1[t] = sc;
                sh1[t] = (b1[t] - m1[t]) * sc + be1[t];
            }
            {
                float sc = g2[t] * rsqrtf(v2[t] + BNEPS);
                sc2[t] = sc;
                sh2[t] = (b2[t] - m2[t]) * sc + be2[t];
            }
            {
                float sc = g3[t] * rsqrtf(v3[t] + BNEPS);
                sc3[t] = sc;
                sh3[t] = (b3[t] - m3[t]) * sc + be3[t];
            }
        }
    }
}

// ---------------- layer-1 feature transform (K=5); h fp8, rout bf16 ----------

__global__ __launch_bounds__(256) void feat1_kernel(
    const float* __restrict__ xin, const float* __restrict__ W,
    const float* __restrict__ pw, const float* __restrict__ pb,
    const float* __restrict__ a_src, const float* __restrict__ a_dst,
    unsigned char* __restrict__ h8, float* __restrict__ esrc, float* __restrict__ edst,
    unsigned short* __restrict__ rout16, int nN)
{
    constexpr int F_IN = 5, F_OUT = 64;
    int t = threadIdx.x;
    int n = blockIdx.x * 4 + t / F_OUT;
    int f = t % F_OUT;
    if (n >= nN) return;
    float acc = 0.f, racc = 0.f;
#pragma unroll
    for (int k = 0; k < F_IN; ++k) {
        float xv = xin[n * F_IN + k];
        acc  += xv * W[k * F_OUT + f];
        racc += xv * pw[k * F_OUT + f];
    }
    float other = __shfl_xor(acc, 1, 64);
    if ((f & 1) == 0) {
        int p = __builtin_amdgcn_cvt_pk_fp8_f32(acc, other, 0, false);
        *(unsigned short*)(h8 + (size_t)n * F_OUT + f) = (unsigned short)(p & 0xFFFF);
    }
    rout16[(size_t)n * F_OUT + f] = f2bf(racc + pb[f]);
    float es = acc * a_src[f];
    float ed = acc * a_dst[f];
#pragma unroll
    for (int off = 16; off > 0; off >>= 1) {
        es += __shfl_xor(es, off, 32);
        ed += __shfl_xor(ed, off, 32);
    }
    if ((t & 31) == 0) {
        int head = (f >> 5) & 1;
        esrc[n * 2 + head] = es;
        edst[n * 2 + head] = ed;
    }
}

// ---------------- MFMA feature transform (layers 2,3; N=256 = W‖pw) ----------
// R7 WIN: column-split dataflow — each wave owns 2 nt-columns, b-frags loaded
// once into registers, rows stream from LDS. Unchanged.

template<int K>
__global__ __launch_bounds__(512, 4) void mfma_feat_kernel(
    const unsigned short* __restrict__ xin16, const short* __restrict__ wfrag,
    const float* __restrict__ pb,
    const float* __restrict__ a_src, const float* __restrict__ a_dst,
    unsigned char* __restrict__ h8, float* __restrict__ esrc, float* __restrict__ edst,
    unsigned short* __restrict__ rout16)
{
    constexpr int KS = K / 32;    // MFMA k-steps
    constexpr int CH = K / 8;     // 8-feature (16 B) chunks per node row
    __shared__ __align__(16) char smem[1024 * CH + 28672];
    s16x8* xs = (s16x8*)smem;                                              // [4][CH][16] tiles
    unsigned short* h8lds = (unsigned short*)(smem + 1024 * CH);           // [64][72]
    unsigned short* rolds = (unsigned short*)(smem + 1024 * CH + 9216);    // [64][136]
    float2* espart = (float2*)(smem + 1024 * CH + 26624);                  // [4][64] {es,ed}

    const int tid = threadIdx.x;
    const int base = blockIdx.x * 64;

    for (int idx = tid; idx < 64 * CH; idx += 512) {
        int node = idx / CH;
        int ch = idx % CH;
        int gn = base + node; if (gn > NN - 1) gn = NN - 1;
        s16x8 v = *(const s16x8*)(xin16 + (size_t)gn * K + ch * 8);
        int tt = node >> 4, mm = node & 15;
        xs[(tt * CH + ch) * 16 + mm] = v;
    }
    __syncthreads();

    const int w = tid >> 6;             // 0..7: column-pair owner
    const int lane = tid & 63;
    const int quad = lane >> 4;
    const int m = lane & 15;
    const int nt0 = 2 * w, nt1 = nt0 + 1;

    // b-fragments for this wave's two output columns: loaded ONCE.
    s16x8 bA[2 * KS], bB[2 * KS];
#pragma unroll
    for (int i = 0; i < 2 * KS; ++i) {
        bA[i] = *(const s16x8*)(wfrag + (size_t)((nt0 * KS * 2 + i) * 64 + lane) * 8);
        bB[i] = *(const s16x8*)(wfrag + (size_t)((nt1 * KS * 2 + i) * 64 + lane) * 8);
    }

    const bool hpart = (w < 4);
    float av0 = 0.f, dv0 = 0.f, av1 = 0.f, dv1 = 0.f, bv0 = 0.f, bv1 = 0.f;
    if (hpart) {
        av0 = a_src[nt0 * 16 + m]; dv0 = a_dst[nt0 * 16 + m];
        av1 = a_src[nt1 * 16 + m]; dv1 = a_dst[nt1 * 16 + m];
    } else {
        bv0 = pb[(nt0 - 8) * 16 + m]; bv1 = pb[(nt1 - 8) * 16 + m];
    }

#pragma unroll
    for (int rt = 0; rt < 4; ++rt) {
        s16x8 a[KS];
#pragma unroll
        for (int ks = 0; ks < KS; ++ks)
            a[ks] = xs[(rt * CH + ks * 4 + quad) * 16 + m];
        f32x4v cA = {0.f, 0.f, 0.f, 0.f};
        f32x4v cB = {0.f, 0.f, 0.f, 0.f};
#pragma unroll
        for (int ks = 0; ks < KS; ++ks) {
            cA = __builtin_amdgcn_mfma_f32_16x16x32_bf16(a[ks], bA[2 * ks + 0], cA, 0, 0, 0);
            cA = __builtin_amdgcn_mfma_f32_16x16x32_bf16(a[ks], bA[2 * ks + 1], cA, 0, 0, 0);
            cB = __builtin_amdgcn_mfma_f32_16x16x32_bf16(a[ks], bB[2 * ks + 0], cB, 0, 0, 0);
            cB = __builtin_amdgcn_mfma_f32_16x16x32_bf16(a[ks], bB[2 * ks + 1], cB, 0, 0, 0);
        }
        int row0 = rt * 16 + quad * 4;
        if (hpart) {
#pragma unroll
            for (int r = 0; r < 4; ++r) {
                float v0 = cA[r], v1 = cB[r];
                float es = v0 * av0 + v1 * av1;
                float ed = v0 * dv0 + v1 * dv1;
#pragma unroll
                for (int off = 8; off > 0; off >>= 1) {
                    es += __shfl_xor(es, off, 16);
                    ed += __shfl_xor(ed, off, 16);
                }
                if (m == 0) espart[w * 64 + row0 + r] = make_float2(es, ed);
                float p0 = __shfl_xor(v0, 1, 16);
                float p1 = __shfl_xor(v1, 1, 16);
                if ((m & 1) == 0) {
                    int pk0 = __builtin_amdgcn_cvt_pk_fp8_f32(v0, p0, 0, false);
                    int pk1 = __builtin_amdgcn_cvt_pk_fp8_f32(v1, p1, 0, false);
                    h8lds[(row0 + r) * 72 + nt0 * 8 + (m >> 1)] = (unsigned short)(pk0 & 0xFFFF);
                    h8lds[(row0 + r) * 72 + nt1 * 8 + (m >> 1)] = (unsigned short)(pk1 & 0xFFFF);
                }
            }
        } else {
#pragma unroll
            for (int r = 0; r < 4; ++r) {
                rolds[(row0 + r) * 136 + (nt0 - 8) * 16 + m] = f2bf(cA[r] + bv0);
                rolds[(row0 + r) * 136 + (nt1 - 8) * 16 + m] = f2bf(cB[r] + bv1);
            }
        }
    }

    __syncthreads();

    // es/ed cross-wave reduce: head0 = waves 0,1 (cols 0..63); head1 = waves 2,3.
    if (tid < 64) {
        int node = base + tid;
        if (node < NN) {
            float2 e0 = espart[0 * 64 + tid];
            float2 e1 = espart[1 * 64 + tid];
            float2 e2 = espart[2 * 64 + tid];
            float2 e3 = espart[3 * 64 + tid];
            ((float2*)esrc)[node] = make_float2(e0.x + e1.x, e2.x + e3.x);
            ((float2*)edst)[node] = make_float2(e0.y + e1.y, e2.y + e3.y);
        }
    }
    for (int i = tid; i < 64 * 8; i += 512) {
        int row = i >> 3, ch = i & 7;
        int node = base + row;
        if (node < NN) {
            int4 v = *(const int4*)((char*)h8lds + row * 144 + ch * 16);
            *(int4*)(h8 + (size_t)node * 128 + ch * 16) = v;
        }
    }
    for (int i = tid; i < 64 * 16; i += 512) {
        int row = i >> 4, ch = i & 15;
        int node = base + row;
        if (node < NN) {
            int4 v = *(const int4*)((char*)rolds + row * 272 + ch * 16);
            *(int4*)((char*)rout16 + (size_t)node * 256 + ch * 16) = v;
        }
    }
}

// ---------------- fused aggregate+edgew, F=128 (two nodes/wave) --------------
// R10: edge softmax weights computed IN-KERNEL (lanes 0-15 of each half
// compute one (edge,head) weight each; 16-31 mirror — whole-wave VALU is
// lockstep so duplicates are free). 8 __shfl broadcasts/iter replace the
// csr_w read; the edgew kernels and the csr_w buffer are deleted.

__global__ __launch_bounds__(256) void aggregate128_kernel(
    const unsigned char* __restrict__ h8,
    const int* __restrict__ row2_start, const int* __restrict__ row2_deg,
    const int* __restrict__ csr2_src,
    const float* __restrict__ esrc, const float2* __restrict__ edst,
    const float* __restrict__ bnsc, const float* __restrict__ bnsh,
    unsigned short* __restrict__ io16)
{
    int w = threadIdx.x >> 6;
    int lane = threadIdx.x & 63;
    int half = lane >> 5;
    int hl = lane & 31;
    int fl = hl;                         // dword within the 128 B row
    bool headhi = fl >= 16;
    int e = hl & 7;                      // compute-role edge
    int chead = (hl >> 3) & 1;           // compute-role head
    int bsrc = half * 32 + (headhi ? 8 : 0);
    int n = blockIdx.x * 8 + w * 2 + half;
    float2 edv = edst[n];
    float edh = chead ? edv.y : edv.x;
    int s2 = row2_start[n];
    int dg = row2_deg[n];
    int pc = (dg + 7) & ~7;
    const int4* sp = (const int4*)(csr2_src + s2);
    float s = 0.f;
    floatx2 acc01a = {0.f, 0.f}, acc23a = {0.f, 0.f};
    floatx2 acc01b = {0.f, 0.f}, acc23b = {0.f, 0.f};
    for (int j = 0; j < pc; j += 8) {
        int4 ia = sp[(j >> 2) + 0];
        int4 ib = sp[(j >> 2) + 1];
        // compute-role: select edge e's src index (3-level mux)
        int cx = (e & 4) ? ib.x : ia.x;
        int cy = (e & 4) ? ib.y : ia.y;
        int cz = (e & 4) ? ib.z : ia.z;
        int cw = (e & 4) ? ib.w : ia.w;
        int cxy = (e & 1) ? cy : cx;
        int czw = (e & 1) ? cw : cz;
        int ie = (e & 2) ? czw : cxy;
        float esv = esrc[(size_t)ie * 2 + chead];
        float av = esv + edh;
        av = (av > 0.f) ? av : 0.2f * av;
        float g = __expf(av);
        float g0 = __shfl(g, bsrc + 0, 64);
        float g1 = __shfl(g, bsrc + 1, 64);
        float g2 = __shfl(g, bsrc + 2, 64);
        float g3 = __shfl(g, bsrc + 3, 64);
        float g4 = __shfl(g, bsrc + 4, 64);
        float g5 = __shfl(g, bsrc + 5, 64);
        float g6 = __shfl(g, bsrc + 6, 64);
        float g7 = __shfl(g, bsrc + 7, 64);
        unsigned d0 = *(const unsigned*)(h8 + (size_t)ia.x * 128 + fl * 4);
        unsigned d1 = *(const unsigned*)(h8 + (size_t)ia.y * 128 + fl * 4);
        unsigned d2 = *(const unsigned*)(h8 + (size_t)ia.z * 128 + fl * 4);
        unsigned d3 = *(const unsigned*)(h8 + (size_t)ia.w * 128 + fl * 4);
        unsigned d4 = *(const unsigned*)(h8 + (size_t)ib.x * 128 + fl * 4);
        unsigned d5 = *(const unsigned*)(h8 + (size_t)ib.y * 128 + fl * 4);
        unsigned d6 = *(const unsigned*)(h8 + (size_t)ib.z * 128 + fl * 4);
        unsigned d7 = *(const unsigned*)(h8 + (size_t)ib.w * 128 + fl * 4);
        floatx2 gv0 = {g0, g0};
        floatx2 gv1 = {g1, g1};
        floatx2 gv2 = {g2, g2};
        floatx2 gv3 = {g3, g3};
        floatx2 gv4 = {g4, g4};
        floatx2 gv5 = {g5, g5};
        floatx2 gv6 = {g6, g6};
        floatx2 gv7 = {g7, g7};
        acc01a = pkfma(gv0, __builtin_amdgcn_cvt_pk_f32_fp8((int)d0, false), acc01a);
        acc23a = pkfma(gv0, __builtin_amdgcn_cvt_pk_f32_fp8((int)d0, true),  acc23a);
        acc01a = pkfma(gv1, __builtin_amdgcn_cvt_pk_f32_fp8((int)d1, false), acc01a);
        acc23a = pkfma(gv1, __builtin_amdgcn_cvt_pk_f32_fp8((int)d1, true),  acc23a);
        acc01a = pkfma(gv2, __builtin_amdgcn_cvt_pk_f32_fp8((int)d2, false), acc01a);
        acc23a = pkfma(gv2, __builtin_amdgcn_cvt_pk_f32_fp8((int)d2, true),  acc23a);
        acc01a = pkfma(gv3, __builtin_amdgcn_cvt_pk_f32_fp8((int)d3, false), acc01a);
        acc23a = pkfma(gv3, __builtin_amdgcn_cvt_pk_f32_fp8((int)d3, true),  acc23a);
        acc01b = pkfma(gv4, __builtin_amdgcn_cvt_pk_f32_fp8((int)d4, false), acc01b);
        acc23b = pkfma(gv4, __builtin_amdgcn_cvt_pk_f32_fp8((int)d4, true),  acc23b);
        acc01b = pkfma(gv5, __builtin_amdgcn_cvt_pk_f32_fp8((int)d5, false), acc01b);
        acc23b = pkfma(gv5, __builtin_amdgcn_cvt_pk_f32_fp8((int)d5, true),  acc23b);
        acc01b = pkfma(gv6, __builtin_amdgcn_cvt_pk_f32_fp8((int)d6, false), acc01b);
        acc23b = pkfma(gv6, __builtin_amdgcn_cvt_pk_f32_fp8((int)d6, true),  acc23b);
        acc01b = pkfma(gv7, __builtin_amdgcn_cvt_pk_f32_fp8((int)d7, false), acc01b);
        acc23b = pkfma(gv7, __builtin_amdgcn_cvt_pk_f32_fp8((int)d7, true),  acc23b);
        s += (((g0 + g1) + (g2 + g3)) + ((g4 + g5) + (g6 + g7)));
    }
    floatx2 acc01 = acc01a + acc01b;
    floatx2 acc23 = acc23a + acc23b;
    float inv = 1.f / (s + 1e-16f);
    int f0 = fl * 4;
    float4 sc = *(const float4*)(bnsc + f0);
    float4 sh = *(const float4*)(bnsh + f0);
    float o0 = fmaf(acc01.x * inv, sc.x, sh.x);
    float o1 = fmaf(acc01.y * inv, sc.y, sh.y);
    float o2 = fmaf(acc23.x * inv, sc.z, sh.z);
    float o3 = fmaf(acc23.y * inv, sc.w, sh.w);
    uint2* iop = (uint2*)(io16 + (size_t)n * 128 + f0);
    uint2 pu = *iop;
    float r0 = fmaxf(o0, 0.f) + __uint_as_float((pu.x & 0xFFFFu) << 16);
    float r1 = fmaxf(o1, 0.f) + __uint_as_float(pu.x & 0xFFFF0000u);
    float r2 = fmaxf(o2, 0.f) + __uint_as_float((pu.y & 0xFFFFu) << 16);
    float r3 = fmaxf(o3, 0.f) + __uint_as_float(pu.y & 0xFFFF0000u);
    uint2 ov;
    ov.x = (unsigned)f2bf(r0) | ((unsigned)f2bf(r1) << 16);
    ov.y = (unsigned)f2bf(r2) | ((unsigned)f2bf(r3) << 16);
    *iop = ov;
}

// ---------------- fused aggregate+edgew, F=64 (two nodes/wave) ---------------

__global__ __launch_bounds__(256) void aggregate64_kernel(
    const unsigned char* __restrict__ h8,
    const int* __restrict__ row2_start, const int* __restrict__ row2_deg,
    const int* __restrict__ csr2_src,
    const float* __restrict__ esrc, const float2* __restrict__ edst,
    const float* __restrict__ bnsc, const float* __restrict__ bnsh,
    unsigned short* __restrict__ io16)
{
    int w = threadIdx.x >> 6;
    int lane = threadIdx.x & 63;
    int half = lane >> 5;
    int hl = lane & 31;
    int q  = hl >> 4;                 // edge selector within pair
    int fl = hl & 15;                 // feature dword (features 4fl..4fl+3)
    bool headhi = fl >= 8;
    int e = hl & 7;                   // compute-role edge
    int chead = (hl >> 3) & 1;        // compute-role head
    int bsrc = half * 32 + (headhi ? 8 : 0);
    int n = blockIdx.x * 8 + w * 2 + half;
    float2 edv = edst[n];
    float edh = chead ? edv.y : edv.x;
    int s2 = row2_start[n];
    int dg = row2_deg[n];
    int pc = (dg + 7) & ~7;
    const int4* sp = (const int4*)(csr2_src + s2);
    float s = 0.f;
    floatx2 acc01 = {0.f, 0.f}, acc23 = {0.f, 0.f};
    for (int j = 0; j < pc; j += 8) {
        int4 ia = sp[(j >> 2) + 0];
        int4 ib = sp[(j >> 2) + 1];
        // compute-role weight for edge e, head chead
        int cx = (e & 4) ? ib.x : ia.x;
        int cy = (e & 4) ? ib.y : ia.y;
        int cz = (e & 4) ? ib.z : ia.z;
        int cw = (e & 4) ? ib.w : ia.w;
        int cxy = (e & 1) ? cy : cx;
        int czw = (e & 1) ? cw : cz;
        int iec = (e & 2) ? czw : cxy;
        float esv = esrc[(size_t)iec * 2 + chead];
        float av = esv + edh;
        av = (av > 0.f) ? av : 0.2f * av;
        float g = __expf(av);
        // this lane's 4 edges: {q, 2+q, 4+q, 6+q}
        float g0 = __shfl(g, bsrc + q, 64);
        float g1 = __shfl(g, bsrc + 2 + q, 64);
        float g2 = __shfl(g, bsrc + 4 + q, 64);
        float g3 = __shfl(g, bsrc + 6 + q, 64);
        int i0 = q ? ia.y : ia.x;
        int i1 = q ? ia.w : ia.z;
        int i2 = q ? ib.y : ib.x;
        int i3 = q ? ib.w : ib.z;
        unsigned d0 = *(const unsigned*)(h8 + (size_t)i0 * 64 + fl * 4);
        unsigned d1 = *(const unsigned*)(h8 + (size_t)i1 * 64 + fl * 4);
        unsigned d2 = *(const unsigned*)(h8 + (size_t)i2 * 64 + fl * 4);
        unsigned d3 = *(const unsigned*)(h8 + (size_t)i3 * 64 + fl * 4);
        floatx2 gv0 = {g0, g0};
        floatx2 gv1 = {g1, g1};
        floatx2 gv2 = {g2, g2};
        floatx2 gv3 = {g3, g3};
        acc01 = pkfma(gv0, __builtin_amdgcn_cvt_pk_f32_fp8((int)d0, false), acc01);
        acc23 = pkfma(gv0, __builtin_amdgcn_cvt_pk_f32_fp8((int)d0, true),  acc23);
        acc01 = pkfma(gv1, __builtin_amdgcn_cvt_pk_f32_fp8((int)d1, false), acc01);
        acc23 = pkfma(gv1, __builtin_amdgcn_cvt_pk_f32_fp8((int)d1, true),  acc23);
        acc01 = pkfma(gv2, __builtin_amdgcn_cvt_pk_f32_fp8((int)d2, false), acc01);
        acc23 = pkfma(gv2, __builtin_amdgcn_cvt_pk_f32_fp8((int)d2, true),  acc23);
        acc01 = pkfma(gv3, __builtin_amdgcn_cvt_pk_f32_fp8((int)d3, false), acc01);
        acc23 = pkfma(gv3, __builtin_amdgcn_cvt_pk_f32_fp8((int)d3, true),  acc23);
        s += ((g0 + g1) + (g2 + g3));
    }
    // combine the two quarters within each half (xor 16 stays inside the half)
    acc01.x += __shfl_xor(acc01.x, 16);
    acc01.y += __shfl_xor(acc01.y, 16);
    acc23.x += __shfl_xor(acc23.x, 16);
    acc23.y += __shfl_xor(acc23.y, 16);
    s += __shfl_xor(s, 16);
    if (hl < 16) {
        float inv = 1.f / (s + 1e-16f);
        int f0 = fl * 4;
        float4 sc = *(const float4*)(bnsc + f0);
        float4 sh = *(const float4*)(bnsh + f0);
        float o0 = fmaf(acc01.x * inv, sc.x, sh.x);
        float o1 = fmaf(acc01.y * inv, sc.y, sh.y);
        float o2 = fmaf(acc23.x * inv, sc.z, sh.z);
        float o3 = fmaf(acc23.y * inv, sc.w, sh.w);
        uint2* iop = (uint2*)(io16 + (size_t)n * 64 + f0);
        uint2 pu = *iop;
        float r0 = fmaxf(o0, 0.f) + __uint_as_float((pu.x & 0xFFFFu) << 16);
        float r1 = fmaxf(o1, 0.f) + __uint_as_float(pu.x & 0xFFFF0000u);
        float r2 = fmaxf(o2, 0.f) + __uint_as_float((pu.y & 0xFFFFu) << 16);
        float r3 = fmaxf(o3, 0.f) + __uint_as_float(pu.y & 0xFFFF0000u);
        uint2 ov;
        ov.x = (unsigned)f2bf(r0) | ((unsigned)f2bf(r1) << 16);
        ov.y = (unsigned)f2bf(r2) | ((unsigned)f2bf(r3) << 16);
        *iop = ov;
    }
}

// ---------------- pooling, two-phase (bf16 input) ----------------

__global__ __launch_bounds__(128) void pool_partial_kernel(
    const unsigned short* __restrict__ hf16, const int* __restrict__ batch,
    float* __restrict__ ppart)
{
    int g = blockIdx.x / PSPLIT;
    int p = blockIdx.x % PSPLIT;
    int f = threadIdx.x;
    int lo = 0, hi = NN;
    while (lo < hi) { int mid = (lo + hi) >> 1; if (batch[mid] < g) lo = mid + 1; else hi = mid; }
    int start = lo;
    hi = NN;
    while (lo < hi) { int mid = (lo + hi) >> 1; if (batch[mid] < g + 1) lo = mid + 1; else hi = mid; }
    int end = lo;
    int len = end - start;
    int chunk = (len + PSPLIT - 1) / PSPLIT;
    int i0 = start + p * chunk;
    int i1 = i0 + chunk; if (i1 > end) i1 = end;
    float acc = 0.f;
    for (int i = i0; i < i1; ++i) acc += bf2f(hf16[(size_t)i * 128 + f]);
    ppart[((size_t)g * PSPLIT + p) * 128 + f] = acc;
}

// ---------------- MLP head (folds partial-sum reduce + mean) -----------------

__global__ __launch_bounds__(128) void head_kernel(
    const float* __restrict__ ppart, const int* __restrict__ batch,
    const float* __restrict__ fw, const float* __restrict__ fb,
    const float* __restrict__ g4, const float* __restrict__ be4,
    const float* __restrict__ m4, const float* __restrict__ v4,
    const float* __restrict__ l1w, const float* __restrict__ l1b,
    const float* __restrict__ l2w, const float* __restrict__ l2b,
    float* __restrict__ out)
{
    __shared__ float p[128];
    __shared__ float z1[32];
    __shared__ float z2[32];
    int g = blockIdx.x, t = threadIdx.x;
    int lo = 0, hi = NN;
    while (lo < hi) { int mid = (lo + hi) >> 1; if (batch[mid] < g) lo = mid + 1; else hi = mid; }
    int start = lo;
    hi = NN;
    while (lo < hi) { int mid = (lo + hi) >> 1; if (batch[mid] < g + 1) lo = mid + 1; else hi = mid; }
    float cnt = (float)(lo - start);
    float acc = 0.f;
#pragma unroll
    for (int q = 0; q < PSPLIT; ++q)
        acc += ppart[((size_t)g * PSPLIT + q) * 128 + t];
    p[t] = acc / fmaxf(cnt, 1.0f);
    __syncthreads();
    if (t < 32) {
        float a = fb[t];
        for (int k = 0; k < 128; ++k) a += p[k] * fw[k * 32 + t];
        float val = g4[t] * (a - m4[t]) * rsqrtf(v4[t] + BNEPS) + be4[t];
        z1[t] = fmaxf(val, 0.f);
    }
    __syncthreads();
    if (t < 32) {
        float a = l1b[t];
        for (int k = 0; k < 32; ++k) a += z1[k] * l1w[k * 32 + t];
        z2[t] = fmaxf(a, 0.f);
    }
    __syncthreads();
    if (t < 10) {
        float a = l2b[t];
        for (int k = 0; k < 32; ++k) a += z2[k] * l2w[k * 10 + t];
        out[g * 10 + t] = a;
    }
}

// ---------------- launch ----------------

extern "C" void kernel_launch(void* const* d_in, const int* in_sizes, int n_in,
                              void* d_out, int out_size, void* d_ws, size_t ws_size,
                              hipStream_t stream) {
    const float* x     = (const float*)d_in[0];
    const int*   ei    = (const int*)d_in[1];
    const int*   batch = (const int*)d_in[2];
    const float* w1  = (const float*)d_in[3];
    const float* as1 = (const float*)d_in[4];
    const float* ad1 = (const float*)d_in[5];
    const float* b1  = (const float*)d_in[6];
    const float* g1  = (const float*)d_in[7];
    const float* be1 = (const float*)d_in[8];
    const float* m1  = (const float*)d_in[9];
    const float* v1  = (const float*)d_in[10];
    const float* p1w = (const float*)d_in[11];
    const float* p1b = (const float*)d_in[12];
    const float* w2  = (const float*)d_in[13];
    const float* as2 = (const float*)d_in[14];
    const float* ad2 = (const float*)d_in[15];
    const float* b2  = (const float*)d_in[16];
    const float* g2  = (const float*)d_in[17];
    const float* be2 = (const float*)d_in[18];
    const float* m2  = (const float*)d_in[19];
    const float* v2  = (const float*)d_in[20];
    const float* p2w = (const float*)d_in[21];
    const float* p2b = (const float*)d_in[22];
    const float* w3  = (const float*)d_in[23];
    const float* as3 = (const float*)d_in[24];
    const float* ad3 = (const float*)d_in[25];
    const float* b3  = (const float*)d_in[26];
    const float* g3  = (const float*)d_in[27];
    const float* be3 = (const float*)d_in[28];
    const float* m3  = (const float*)d_in[29];
    const float* v3  = (const float*)d_in[30];
    const float* p3w = (const float*)d_in[31];
    const float* p3b = (const float*)d_in[32];
    const float* fw  = (const float*)d_in[33];
    const float* fb  = (const float*)d_in[34];
    const float* g4  = (const float*)d_in[35];
    const float* be4 = (const float*)d_in[36];
    const float* m4  = (const float*)d_in[37];
    const float* v4  = (const float*)d_in[38];
    const float* l1w = (const float*)d_in[39];
    const float* l1b = (const float*)d_in[40];
    const float* l2w = (const float*)d_in[41];
    const float* l2b = (const float*)d_in[42];

    char* ws = (char*)d_ws;
    size_t off = 0;
    auto alloc = [&](size_t bytes) -> char* {
        char* p = ws + off;
        off += (bytes + 255) & ~(size_t)255;
        return p;
    };
    int*    bucket_cnt  = (int*)alloc((NBK) * sizeof(int));
    int*    bucket_base = (int*)alloc((NBK + 1) * sizeof(int));
    int*    gcursor     = (int*)alloc((NBK) * sizeof(int));
    int*    part        = (int*)alloc((size_t)ETOT * sizeof(int));
    int*    row2_start  = (int*)alloc(NN * sizeof(int));
    int*    row2_deg    = (int*)alloc(NN * sizeof(int));
    int*    csr2_src    = (int*)alloc((size_t)PADTOT * sizeof(int));
    unsigned char*  h8  = (unsigned char*)alloc((size_t)(NN + 1) * 128);
    unsigned short* hb1 = (unsigned short*)alloc((size_t)NN * 64 * sizeof(short));
    unsigned short* hb2 = (unsigned short*)alloc((size_t)NN * 128 * sizeof(short));
    unsigned short* hb3 = (unsigned short*)alloc((size_t)NN * 128 * sizeof(short));
    float*  esrc        = (float*)alloc((size_t)(NN + 1) * 2 * sizeof(float));
    float*  edst        = (float*)alloc((size_t)NN * 2 * sizeof(float));
    float*  ppart       = (float*)alloc((size_t)GG * PSPLIT * 128 * sizeof(float));
    short*  wfrag2      = (short*)alloc((size_t)16 * 2 * 2 * 64 * 8 * sizeof(short));
    short*  wfrag3      = (short*)alloc((size_t)16 * 4 * 2 * 64 * 8 * sizeof(short));
    float*  bnsc1       = (float*)alloc(64 * sizeof(float));
    float*  bnsh1       = (float*)alloc(64 * sizeof(float));
    float*  bnsc2       = (float*)alloc(128 * sizeof(float));
    float*  bnsh2       = (float*)alloc(128 * sizeof(float));
    float*  bnsc3       = (float*)alloc(128 * sizeof(float));
    float*  bnsh3       = (float*)alloc(128 * sizeof(float));

    // ---- merged prep (W fragments + fused BN) ----
    prep_all_kernel<<<49, 256, 0, stream>>>(
        w2, p2w, wfrag2, w3, p3w, wfrag3,
        b1, g1, be1, m1, v1, b2, g2, be2, m2, v2, b3, g3, be3, m3, v3,
        bnsc1, bnsh1, bnsc2, bnsh2, bnsc3, bnsh3);

    // ---- CSR build (bucketed partition, padded-8 layout, NN sentinel) ----
    hipMemsetAsync(bucket_cnt, 0, NBK * sizeof(int), stream);
    bucket_count_kernel<<<(ETOT + 8191) / 8192, 256, 0, stream>>>(ei, bucket_cnt);
    bucket_scan_kernel<<<1, 512, 0, stream>>>(bucket_cnt, bucket_base, gcursor, esrc);
    partition_kernel<<<(ETOT + 4095) / 4096, 256, 0, stream>>>(ei, gcursor, part);
    csr_build_kernel<<<NBK, 256, 0, stream>>>(part, bucket_base, row2_start, row2_deg, csr2_src);

    // ---- layer 1: x[N,5] -> hb1[N,64] (bf16) ----
    feat1_kernel<<<(NN + 3) / 4, 256, 0, stream>>>(
        x, w1, p1w, p1b, as1, ad1, h8, esrc, edst, hb1, NN);
    aggregate64_kernel<<<NN / 8, 256, 0, stream>>>(
        h8, row2_start, row2_deg, csr2_src, esrc, (const float2*)edst, bnsc1, bnsh1, hb1);

    // ---- layer 2: hb1 -> hb2[N,128] (bf16) ----
    mfma_feat_kernel<64><<<(NN + 63) / 64, 512, 0, stream>>>(
        hb1, wfrag2, p2b, as2, ad2, h8, esrc, edst, hb2);
    aggregate128_kernel<<<NN / 8, 256, 0, stream>>>(
        h8, row2_start, row2_deg, csr2_src, esrc, (const float2*)edst, bnsc2, bnsh2, hb2);

    // ---- layer 3: hb2 -> hb3[N,128] (bf16) ----
    mfma_feat_kernel<128><<<(NN + 63) / 64, 512, 0, stream>>>(
        hb2, wfrag3, p3b, as3, ad3, h8, esrc, edst, hb3);
    aggregate128_kernel<<<NN / 8, 256, 0, stream>>>(
        h8, row2_start, row2_deg, csr2_src, esrc, (const float2*)edst, bnsc3, bnsh3, hb3);

    // ---- pool (two-phase) + head ----
    pool_partial_kernel<<<GG * PSPLIT, 128, 0, stream>>>(hb3, batch, ppart);
    head_kernel<<<GG, 128, 0, stream>>>(ppart, batch, fw, fb, g4, be4, m4, v4,
                                        l1w, l1b, l2w, l2b, (float*)d_out);
}